// Round 1
// baseline (886.511 us; speedup 1.0000x reference)
//
#include <hip/hip_runtime.h>

typedef __attribute__((ext_vector_type(8))) __bf16 bf16x8;
typedef __attribute__((ext_vector_type(4))) float f32x4;
typedef __attribute__((ext_vector_type(4))) unsigned short u16x4;
typedef __attribute__((ext_vector_type(8))) unsigned short u16x8;

#define MFMA_BF16 __builtin_amdgcn_mfma_f32_16x16x32_bf16

__device__ __forceinline__ unsigned short f2bf(float f) {
  union { float f; unsigned u; } v; v.f = f;
  unsigned r = v.u + 0x7FFFu + ((v.u >> 16) & 1u);
  return (unsigned short)(r >> 16);
}

__device__ __forceinline__ void gload16(const void* g, void* l) {
  __builtin_amdgcn_global_load_lds(
      (const __attribute__((address_space(1))) unsigned int*)g,
      (__attribute__((address_space(3))) unsigned int*)l, 16, 0, 0);
}

__global__ void __launch_bounds__(256) cast_bf16_kernel(const float* __restrict__ in,
                                                        unsigned short* __restrict__ out,
                                                        int n8) {
  int i = blockIdx.x * 256 + threadIdx.x;
  if (i >= n8) return;
  long base = (long)i * 8;
  float4 a = *(const float4*)(in + base);
  float4 b = *(const float4*)(in + base + 4);
  u16x8 o;
  o[0] = f2bf(a.x); o[1] = f2bf(a.y); o[2] = f2bf(a.z); o[3] = f2bf(a.w);
  o[4] = f2bf(b.x); o[5] = f2bf(b.y); o[6] = f2bf(b.z); o[7] = f2bf(b.w);
  *(u16x8*)(out + base) = o;
}

// row remapping: 0 = identity, 1 = b*825 + 57 + (m % 768), 2 = b*825 + (m % 57)
template <int REMAP>
__device__ __forceinline__ long remap_row(int m) {
  if (REMAP == 1) { int b = m / 768; return (long)b * 825 + 57 + (m - b * 768); }
  if (REMAP == 2) { int b = m / 57;  return (long)b * 825 + (m - b * 57); }
  return m;
}

// C[M,N] = A[M,K=1152] @ B[N,K]^T   (A rows possibly remapped into an 825-stride buffer)
// PROJ: fp32 out with bias, out rows remapped same as A. Else: bf16 out, rows = m.
template <int REMAP, bool PROJ>
__global__ void __launch_bounds__(256) gemm_bt(const unsigned short* __restrict__ A,
                                               const unsigned short* __restrict__ Bw,
                                               void* __restrict__ Cout,
                                               const float* __restrict__ bias,
                                               int M, int N) {
  const int K = 1152;
  __shared__ unsigned short At[128 * 64];
  __shared__ unsigned short Bt[128 * 64];
  int tid = threadIdx.x;
  int lane = tid & 63, wid = tid >> 6;
  int l15 = lane & 15, hi = lane >> 4;
  int wm = wid >> 1, wn = wid & 1;
  int m0 = blockIdx.y * 128, n0 = blockIdx.x * 128;

  const unsigned short* asrc[4];
  const unsigned short* bsrc[4];
  unsigned ldsoff[4];
#pragma unroll
  for (int j = 0; j < 4; j++) {
    int c = tid + j * 256;
    int r = c >> 3;
    int cc = (c & 7) ^ (r & 7);  // pre-swizzled global source chunk (T2, both-sides)
    ldsoff[j] = (unsigned)c * 8;
    int ma = m0 + r; if (ma > M - 1) ma = M - 1;
    asrc[j] = A + remap_row<REMAP>(ma) * K + cc * 8;
    bsrc[j] = Bw + (long)(n0 + r) * K + cc * 8;
  }

  f32x4 acc[4][4] = {};

  for (int kt = 0; kt < K; kt += 64) {
#pragma unroll
    for (int j = 0; j < 4; j++) {
      gload16(asrc[j] + kt, &At[ldsoff[j]]);
      gload16(bsrc[j] + kt, &Bt[ldsoff[j]]);
    }
    __syncthreads();
#pragma unroll
    for (int ks = 0; ks < 2; ks++) {
      bf16x8 af[4], bfr[4];
#pragma unroll
      for (int i = 0; i < 4; i++) {
        int ra = wm * 64 + i * 16 + l15;
        int ca = (ks * 64 + hi * 16) ^ ((ra & 7) << 4);
        af[i] = *(const bf16x8*)((const char*)At + ra * 128 + ca);
        int rb = wn * 64 + i * 16 + l15;
        int cb = (ks * 64 + hi * 16) ^ ((rb & 7) << 4);
        bfr[i] = *(const bf16x8*)((const char*)Bt + rb * 128 + cb);
      }
#pragma unroll
      for (int i = 0; i < 4; i++)
#pragma unroll
        for (int j = 0; j < 4; j++)
          acc[i][j] = MFMA_BF16(af[i], bfr[j], acc[i][j], 0, 0, 0);
    }
    __syncthreads();
  }

#pragma unroll
  for (int j = 0; j < 4; j++) {
    int n = n0 + wn * 64 + j * 16 + l15;
    float bv = 0.f;
    if (PROJ) bv = bias[n];
#pragma unroll
    for (int i = 0; i < 4; i++) {
      int mb = m0 + wm * 64 + i * 16 + hi * 4;
#pragma unroll
      for (int r = 0; r < 4; r++) {
        int m = mb + r;
        if (m < M) {
          if (PROJ)
            ((float*)Cout)[remap_row<REMAP>(m) * N + n] = acc[i][j][r] + bv;
          else
            ((unsigned short*)Cout)[(long)m * N + n] = f2bf(acc[i][j][r]);
        }
      }
    }
  }
}

// ---- non-act attention: one block per (h, g, b); 4 waves, each owns 64 q rows ----
__global__ void __launch_bounds__(256) attn_non(const unsigned short* __restrict__ qkv,
                                                unsigned short* __restrict__ o) {
  int h = blockIdx.x, g = blockIdx.y, b = blockIdx.z;
  __shared__ unsigned short K_s[128 * 104];   // [kk][96 cols padded to 104], cols>=72 zero
  __shared__ unsigned short V_s[80 * 136];    // V^T: [d][kk], rows 72..79 unused garbage
  __shared__ unsigned short P_s[16 * 16 * 40];// [(wid*4+qt)][q][k 0..31, stride 40]
  int tid = threadIdx.x, lane = tid & 63, wid = tid >> 6;
  int l15 = lane & 15, hi = lane >> 4;
  const long base = (long)((b * 3 + g) * 256) * 3456;
  const float SC2 = 0.11785113019775793f * 1.4426950408889634f;

  // Q fragments in registers (B-frag: lane holds Q[q=l15][d=hi*8..+7] per 32-k step)
  bf16x8 qf[4][3];
#pragma unroll
  for (int qt = 0; qt < 4; qt++)
#pragma unroll
    for (int ds = 0; ds < 3; ds++) {
      int q = wid * 64 + qt * 16 + l15;
      int d = ds * 32 + hi * 8;
      if (d < 72)
        qf[qt][ds] = *(const bf16x8*)(qkv + base + (long)q * 3456 + h * 72 + d);
      else {
        u16x8 z = {0, 0, 0, 0, 0, 0, 0, 0};
        qf[qt][ds] = __builtin_bit_cast(bf16x8, z);
      }
    }

  f32x4 ot[5][4] = {};
  float lsum[4] = {0.f, 0.f, 0.f, 0.f};

  for (int c0 = 0; c0 < 256; c0 += 128) {
    {  // stage K chunk (qkv slot 1)
      int r = tid >> 1, hf = tid & 1;
      const unsigned short* src = qkv + base + (long)(c0 + r) * 3456 + (16 + h) * 72 + hf * 48;
      unsigned short* dst = &K_s[r * 104 + hf * 48];
#pragma unroll
      for (int j = 0; j < 6; j++) {
        int col = hf * 48 + j * 8;
        u16x8 v = {0, 0, 0, 0, 0, 0, 0, 0};
        if (col < 72) v = *(const u16x8*)(src + j * 8);
        *(u16x8*)(dst + j * 8) = v;
      }
    }
    if (tid < 128) {  // stage V^T (qkv slot 2): token c0+tid -> column tid
      const unsigned short* src = qkv + base + (long)(c0 + tid) * 3456 + (32 + h) * 72;
      u16x8 w[9];
#pragma unroll
      for (int j = 0; j < 9; j++) w[j] = *(const u16x8*)(src + j * 8);
#pragma unroll
      for (int j = 0; j < 9; j++)
#pragma unroll
        for (int e = 0; e < 8; e++) V_s[(j * 8 + e) * 136 + tid] = w[j][e];
    }
    __syncthreads();

#pragma unroll
    for (int k32 = 0; k32 < 4; k32++) {
#pragma unroll
      for (int kt = 0; kt < 2; kt++) {
        bf16x8 kf[3];
#pragma unroll
        for (int ds = 0; ds < 3; ds++)
          kf[ds] = *(const bf16x8*)((const char*)K_s +
                     ((k32 * 32 + kt * 16 + l15) * 104 + ds * 32 + hi * 8) * 2);
#pragma unroll
        for (int qt = 0; qt < 4; qt++) {
          f32x4 st = {};
#pragma unroll
          for (int ds = 0; ds < 3; ds++) st = MFMA_BF16(kf[ds], qf[qt][ds], st, 0, 0, 0);
          u16x4 pw;
#pragma unroll
          for (int r = 0; r < 4; r++) {
            float p = exp2f(st[r] * SC2);  // no-max softmax (|logit*scale| ~ <10)
            lsum[qt] += p;
            pw[r] = f2bf(p);
          }
          *(u16x4*)&P_s[((wid * 4 + qt) * 16 + l15) * 40 + kt * 16 + hi * 4] = pw;
        }
      }
      // PV: O^T += V^T · P^T   (per-wave-private P_s; compiler inserts lgkm waits)
      bf16x8 pf[4];
#pragma unroll
      for (int qt = 0; qt < 4; qt++)
        pf[qt] = *(const bf16x8*)&P_s[((wid * 4 + qt) * 16 + l15) * 40 + hi * 8];
#pragma unroll
      for (int dt = 0; dt < 5; dt++) {
        bf16x8 vf = *(const bf16x8*)&V_s[(dt * 16 + l15) * 136 + k32 * 32 + hi * 8];
#pragma unroll
        for (int qt = 0; qt < 4; qt++) ot[dt][qt] = MFMA_BF16(vf, pf[qt], ot[dt][qt], 0, 0, 0);
      }
    }
    __syncthreads();
  }

#pragma unroll
  for (int qt = 0; qt < 4; qt++) {
    float s = lsum[qt];
    s += __shfl_xor(s, 16);
    s += __shfl_xor(s, 32);
    lsum[qt] = 1.0f / s;
  }
#pragma unroll
  for (int dt = 0; dt < 5; dt++)
#pragma unroll
    for (int qt = 0; qt < 4; qt++)
#pragma unroll
      for (int r = 0; r < 4; r++) {
        int d = dt * 16 + hi * 4 + r;
        if (d < 72) {
          long row = (long)b * 825 + 57 + g * 256 + wid * 64 + qt * 16 + l15;
          o[row * 1152 + h * 72 + d] = f2bf(ot[dt][qt][r] * lsum[qt]);
        }
      }
}

// ---- act attention: one block per (h, b); 4 waves, each owns one 16-q tile (57 q) ----
__global__ void __launch_bounds__(256) attn_act(const unsigned short* __restrict__ kv,
                                                const unsigned short* __restrict__ qa,
                                                unsigned short* __restrict__ o) {
  int h = blockIdx.x, b = blockIdx.y;
  __shared__ unsigned short K_s[128 * 104];
  __shared__ unsigned short V_s[80 * 136];
  __shared__ unsigned short P_s[4 * 16 * 40];
  int tid = threadIdx.x, lane = tid & 63, wid = tid >> 6;
  int l15 = lane & 15, hi = lane >> 4;
  const float SC2 = 0.11785113019775793f * 1.4426950408889634f;
  const int LIM = 769;

  bf16x8 qf[3];
  {
    int q = wid * 16 + l15; if (q > 56) q = 56;
#pragma unroll
    for (int ds = 0; ds < 3; ds++) {
      int d = ds * 32 + hi * 8;
      if (d < 72)
        qf[ds] = *(const bf16x8*)(qa + (long)(b * 57 + q) * 1152 + h * 72 + d);
      else {
        u16x8 z = {0, 0, 0, 0, 0, 0, 0, 0};
        qf[ds] = __builtin_bit_cast(bf16x8, z);
      }
    }
  }

  f32x4 ot[5] = {};
  float lsum = 0.f;
  const long kbase = (long)b * 825 + 56;

  for (int c0 = 0; c0 < LIM; c0 += 128) {
    int valid = LIM - c0; if (valid > 128) valid = 128;
    {
      int r = tid >> 1, hf = tid & 1;
      int rr = r < valid ? r : valid - 1;  // clamp: finite dup rows, masked in P
      const unsigned short* src = kv + (kbase + c0 + rr) * 2304 + h * 72 + hf * 48;
      unsigned short* dst = &K_s[r * 104 + hf * 48];
#pragma unroll
      for (int j = 0; j < 6; j++) {
        int col = hf * 48 + j * 8;
        u16x8 v = {0, 0, 0, 0, 0, 0, 0, 0};
        if (col < 72) v = *(const u16x8*)(src + j * 8);
        *(u16x8*)(dst + j * 8) = v;
      }
    }
    if (tid < 128) {
      int rr = tid < valid ? tid : valid - 1;
      const unsigned short* src = kv + (kbase + c0 + rr) * 2304 + (16 + h) * 72;
      u16x8 w[9];
#pragma unroll
      for (int j = 0; j < 9; j++) w[j] = *(const u16x8*)(src + j * 8);
#pragma unroll
      for (int j = 0; j < 9; j++)
#pragma unroll
        for (int e = 0; e < 8; e++) V_s[(j * 8 + e) * 136 + tid] = w[j][e];
    }
    __syncthreads();

#pragma unroll
    for (int k32 = 0; k32 < 4; k32++) {
#pragma unroll
      for (int kt = 0; kt < 2; kt++) {
        bf16x8 kf[3];
#pragma unroll
        for (int ds = 0; ds < 3; ds++)
          kf[ds] = *(const bf16x8*)((const char*)K_s +
                     ((k32 * 32 + kt * 16 + l15) * 104 + ds * 32 + hi * 8) * 2);
        f32x4 st = {};
#pragma unroll
        for (int ds = 0; ds < 3; ds++) st = MFMA_BF16(kf[ds], qf[ds], st, 0, 0, 0);
        u16x4 pw;
#pragma unroll
        for (int r = 0; r < 4; r++) {
          int kg = c0 + k32 * 32 + kt * 16 + hi * 4 + r;
          float p = (kg < LIM) ? exp2f(st[r] * SC2) : 0.f;
          lsum += p;
          pw[r] = f2bf(p);
        }
        *(u16x4*)&P_s[(wid * 16 + l15) * 40 + kt * 16 + hi * 4] = pw;
      }
      bf16x8 pf = *(const bf16x8*)&P_s[(wid * 16 + l15) * 40 + hi * 8];
#pragma unroll
      for (int dt = 0; dt < 5; dt++) {
        bf16x8 vf = *(const bf16x8*)&V_s[(dt * 16 + l15) * 136 + k32 * 32 + hi * 8];
        ot[dt] = MFMA_BF16(vf, pf, ot[dt], 0, 0, 0);
      }
    }
    __syncthreads();
  }

  {
    float s = lsum;
    s += __shfl_xor(s, 16);
    s += __shfl_xor(s, 32);
    lsum = 1.0f / s;
  }
  int q = wid * 16 + l15;
#pragma unroll
  for (int dt = 0; dt < 5; dt++)
#pragma unroll
    for (int r = 0; r < 4; r++) {
      int d = dt * 16 + hi * 4 + r;
      if (d < 72 && q < 57)
        o[((long)b * 825 + q) * 1152 + h * 72 + d] = f2bf(ot[dt][r] * lsum);
    }
}

extern "C" void kernel_launch(void* const* d_in, const int* in_sizes, int n_in,
                              void* d_out, int out_size, void* d_ws, size_t ws_size,
                              hipStream_t stream) {
  const float* x     = (const float*)d_in[0];
  const float* w_qkv = (const float*)d_in[1];
  const float* w_q   = (const float*)d_in[2];
  const float* w_kv  = (const float*)d_in[3];
  const float* w_pn  = (const float*)d_in[4];
  const float* b_pn  = (const float*)d_in[5];
  const float* w_pa  = (const float*)d_in[6];
  const float* b_pa  = (const float*)d_in[7];

  char* ws = (char*)d_ws;
  unsigned short* xb    = (unsigned short*)ws; ws += (size_t)26400 * 1152 * 2;
  unsigned short* wqkvb = (unsigned short*)ws; ws += (size_t)3456 * 1152 * 2;
  unsigned short* wqb   = (unsigned short*)ws; ws += (size_t)1152 * 1152 * 2;
  unsigned short* wkvb  = (unsigned short*)ws; ws += (size_t)2304 * 1152 * 2;
  unsigned short* wpnb  = (unsigned short*)ws; ws += (size_t)1152 * 1152 * 2;
  unsigned short* wpab  = (unsigned short*)ws; ws += (size_t)1152 * 1152 * 2;
  unsigned short* qkvw  = (unsigned short*)ws; ws += (size_t)24576 * 3456 * 2;
  unsigned short* kvw   = (unsigned short*)ws; ws += (size_t)26400 * 2304 * 2;
  unsigned short* qw    = (unsigned short*)ws; ws += (size_t)1824 * 1152 * 2;
  unsigned short* attnw = (unsigned short*)ws; ws += (size_t)26400 * 1152 * 2;

  auto cast = [&](const float* src, unsigned short* dst, long n) {
    int n8 = (int)(n / 8);
    cast_bf16_kernel<<<(n8 + 255) / 256, 256, 0, stream>>>(src, dst, n8);
  };
  cast(x,     xb,    26400L * 1152);
  cast(w_qkv, wqkvb, 3456L * 1152);
  cast(w_q,   wqb,   1152L * 1152);
  cast(w_kv,  wkvb,  2304L * 1152);
  cast(w_pn,  wpnb,  1152L * 1152);
  cast(w_pa,  wpab,  1152L * 1152);

  // qkv_non = x[:,57:] @ w_qkv^T   (M=32*768, N=3456)
  gemm_bt<1, false><<<dim3(27, 192), 256, 0, stream>>>(xb, wqkvb, qkvw, nullptr, 24576, 3456);
  // kv_act = x @ w_kv^T            (M=32*825, N=2304)
  gemm_bt<0, false><<<dim3(18, 207), 256, 0, stream>>>(xb, wkvb, kvw, nullptr, 26400, 2304);
  // q_act = x[:,:57] @ w_q^T       (M=32*57, N=1152)
  gemm_bt<2, false><<<dim3(9, 15), 256, 0, stream>>>(xb, wqb, qw, nullptr, 1824, 1152);

  attn_non<<<dim3(16, 3, 32), 256, 0, stream>>>(qkvw, attnw);
  attn_act<<<dim3(16, 32), 256, 0, stream>>>(kvw, qw, attnw);

  // projections straight into d_out (fp32), rows remapped to [act | non] layout
  gemm_bt<1, true><<<dim3(9, 192), 256, 0, stream>>>(attnw, wpnb, d_out, b_pn, 24576, 1152);
  gemm_bt<2, true><<<dim3(9, 15), 256, 0, stream>>>(attnw, wpab, d_out, b_pa, 1824, 1152);
}

// Round 2
// 864.144 us; speedup vs baseline: 1.0259x; 1.0259x over previous
//
#include <hip/hip_runtime.h>

typedef __attribute__((ext_vector_type(8))) __bf16 bf16x8;
typedef __attribute__((ext_vector_type(4))) float f32x4;
typedef __attribute__((ext_vector_type(4))) unsigned short u16x4;
typedef __attribute__((ext_vector_type(8))) unsigned short u16x8;

#define MFMA_BF16 __builtin_amdgcn_mfma_f32_16x16x32_bf16

__device__ __forceinline__ unsigned short f2bf(float f) {
  union { float f; unsigned u; } v; v.f = f;
  unsigned r = v.u + 0x7FFFu + ((v.u >> 16) & 1u);
  return (unsigned short)(r >> 16);
}

__device__ __forceinline__ void gload16(const void* g, void* l) {
  __builtin_amdgcn_global_load_lds(
      (const __attribute__((address_space(1))) unsigned int*)g,
      (__attribute__((address_space(3))) unsigned int*)l, 16, 0, 0);
}

__global__ void __launch_bounds__(256) cast_bf16_kernel(const float* __restrict__ in,
                                                        unsigned short* __restrict__ out,
                                                        int n8) {
  int i = blockIdx.x * 256 + threadIdx.x;
  if (i >= n8) return;
  long base = (long)i * 8;
  float4 a = *(const float4*)(in + base);
  float4 b = *(const float4*)(in + base + 4);
  u16x8 o;
  o[0] = f2bf(a.x); o[1] = f2bf(a.y); o[2] = f2bf(a.z); o[3] = f2bf(a.w);
  o[4] = f2bf(b.x); o[5] = f2bf(b.y); o[6] = f2bf(b.z); o[7] = f2bf(b.w);
  *(u16x8*)(out + base) = o;
}

// row remapping: 0 = identity, 1 = b*825 + 57 + (m % 768), 2 = b*825 + (m % 57)
template <int REMAP>
__device__ __forceinline__ long remap_row(int m) {
  if (REMAP == 1) { int b = m / 768; return (long)b * 825 + 57 + (m - b * 768); }
  if (REMAP == 2) { int b = m / 57;  return (long)b * 825 + (m - b * 57); }
  return m;
}

// ============ 256x256 tile, BK=64, 8-wave, 4-phase/K-tile counted-vmcnt GEMM ============
// C[M,N] = A[M,1152] @ B[N,1152]^T. LDS: A-ring 4 slots + B-ring 4 slots, slot=[256][32] bf16.
// Stage stream ht[j]: j=4t+2h+e (e:0=A,1=B, h=k-half). Phase p=4t+q stages ht[p+6].
// vmcnt(4) at q==3 only (vmcnt(0) for the last two K-tiles' waits).
template <int REMAP, bool PROJ>
__global__ void __launch_bounds__(512, 2) gemm256(const unsigned short* __restrict__ A,
                                                  const unsigned short* __restrict__ Bw,
                                                  void* __restrict__ Cout,
                                                  const float* __restrict__ bias,
                                                  int M, int N) {
  const int K = 1152;
  __shared__ unsigned short L[65536];  // 128 KiB: A slots [0,32768), B slots [32768,65536)
  unsigned short* Al = L;
  unsigned short* Bl = L + 32768;
  int tid = threadIdx.x;
  int lane = tid & 63;
  int wid = tid >> 6;
  int l15 = lane & 15, hi = lane >> 4;
  int wm = wid >> 2, wn = wid & 3;

  // bijective XCD swizzle (all grids used are divisible by 8)
  int gx = gridDim.x;
  int nwg = gx * gridDim.y;
  int orig = blockIdx.y * gx + blockIdx.x;
  int q8 = nwg >> 3, r8 = nwg & 7;
  int xcd = orig & 7, off = orig >> 3;
  int wgid = (xcd < r8 ? xcd * (q8 + 1) : r8 * (q8 + 1) + (xcd - r8) * q8) + off;
  int bn = wgid % gx, bm = wgid / gx;
  int m0 = bm * 256, n0 = bn * 256;

  // staging geometry: thread stages 16B at slot-bytes tid*16 and tid*16+8192
  int rlo = tid >> 2;                         // 0..127 (row within half)
  int cg = ((tid & 3) - (tid >> 4)) & 3;      // global k-chunk for local chunk (tid&3)
  int ma0 = m0 + rlo;       if (ma0 > M - 1) ma0 = M - 1;
  int ma1 = m0 + rlo + 128; if (ma1 > M - 1) ma1 = M - 1;
  const unsigned short* aptr0 = A + remap_row<REMAP>(ma0) * K + cg * 8;
  const unsigned short* aptr1 = A + remap_row<REMAP>(ma1) * K + cg * 8;
  int nb0 = n0 + rlo;       if (nb0 > N - 1) nb0 = N - 1;
  int nb1 = n0 + rlo + 128; if (nb1 > N - 1) nb1 = N - 1;
  const unsigned short* bptr0 = Bw + (long)nb0 * K + cg * 8;
  const unsigned short* bptr1 = Bw + (long)nb1 * K + cg * 8;
  unsigned ldst = (unsigned)tid * 8;  // element offset within slot

  auto stageA = [&](int tt, int hh) {
    int koff = tt * 64 + hh * 32;
    unsigned short* d = Al + (((2 * tt + hh) & 3) << 13) + ldst;
    gload16(aptr0 + koff, d);
    gload16(aptr1 + koff, d + 4096);
  };
  auto stageB = [&](int tt, int hh) {
    int koff = tt * 64 + hh * 32;
    unsigned short* d = Bl + (((2 * tt + hh) & 3) << 13) + ldst;
    gload16(bptr0 + koff, d);
    gload16(bptr1 + koff, d + 4096);
  };

  // prologue: ht[0..5] = A(0,0) B(0,0) A(0,1) B(0,1) A(1,0) B(1,0)
  stageA(0, 0); stageB(0, 0); stageA(0, 1); stageB(0, 1);
  __builtin_amdgcn_sched_barrier(0);
  stageA(1, 0); stageB(1, 0);
  __builtin_amdgcn_sched_barrier(0);
  asm volatile("s_waitcnt vmcnt(4)" ::: "memory");  // K-tile 0 landed
  __builtin_amdgcn_s_barrier();
  __builtin_amdgcn_sched_barrier(0);

  f32x4 acc[8][4] = {};
  bf16x8 bfr[4];

  for (int t = 0; t < 18; ++t) {
#pragma unroll
    for (int q = 0; q < 4; ++q) {
      const int h = q >> 1, mh = q & 1;
      const int slot = (2 * t + h) & 3;
      bf16x8 af[4];
#pragma unroll
      for (int f = 0; f < 4; ++f) {
        int row = wm * 128 + mh * 64 + f * 16 + l15;
        int cl = (hi + (row >> 2)) & 3;
        af[f] = *(const bf16x8*)(Al + (slot << 13) + row * 32 + cl * 8);
      }
      if (mh == 0) {
#pragma unroll
        for (int f = 0; f < 4; ++f) {
          int row = wn * 64 + f * 16 + l15;
          int cl = (hi + (row >> 2)) & 3;
          bfr[f] = *(const bf16x8*)(Bl + (slot << 13) + row * 32 + cl * 8);
        }
      }
      // stage ht[p+6]
      if (q == 0)      { if (t + 1 < 18) stageA(t + 1, 1); }
      else if (q == 1) { if (t + 1 < 18) stageB(t + 1, 1); }
      else if (q == 2) { if (t + 2 < 18) stageA(t + 2, 0); }
      else             { if (t + 2 < 18) stageB(t + 2, 0); }
      __builtin_amdgcn_s_barrier();
      __builtin_amdgcn_s_setprio(1);
#pragma unroll
      for (int fm = 0; fm < 4; ++fm)
#pragma unroll
        for (int fn = 0; fn < 4; ++fn)
          acc[mh * 4 + fm][fn] = MFMA_BF16(af[fm], bfr[fn], acc[mh * 4 + fm][fn], 0, 0, 0);
      __builtin_amdgcn_s_setprio(0);
      if (q == 3) {
        if (t < 16) asm volatile("s_waitcnt vmcnt(4)" ::: "memory");
        else        asm volatile("s_waitcnt vmcnt(0)" ::: "memory");
      }
      __builtin_amdgcn_sched_barrier(0);
      __builtin_amdgcn_s_barrier();
      __builtin_amdgcn_sched_barrier(0);
    }
  }

#pragma unroll
  for (int fn = 0; fn < 4; ++fn) {
    int n = n0 + wn * 64 + fn * 16 + l15;
    if (n < N) {
      float bv = 0.f;
      if (PROJ) bv = bias[n];
#pragma unroll
      for (int a = 0; a < 8; ++a) {
        int mb = m0 + wm * 128 + (a >> 2) * 64 + (a & 3) * 16 + hi * 4;
#pragma unroll
        for (int r = 0; r < 4; ++r) {
          int m = mb + r;
          if (m < M) {
            if (PROJ)
              ((float*)Cout)[remap_row<REMAP>(m) * N + n] = acc[a][fn][r] + bv;
            else
              ((unsigned short*)Cout)[(long)m * N + n] = f2bf(acc[a][fn][r]);
          }
        }
      }
    }
  }
}

// ============ 128x128 tile GEMM (kept for the two small GEMMs) ============
template <int REMAP, bool PROJ>
__global__ void __launch_bounds__(256) gemm_bt(const unsigned short* __restrict__ A,
                                               const unsigned short* __restrict__ Bw,
                                               void* __restrict__ Cout,
                                               const float* __restrict__ bias,
                                               int M, int N) {
  const int K = 1152;
  __shared__ unsigned short At[128 * 64];
  __shared__ unsigned short Bt[128 * 64];
  int tid = threadIdx.x;
  int lane = tid & 63, wid = tid >> 6;
  int l15 = lane & 15, hi = lane >> 4;
  int wm = wid >> 1, wn = wid & 1;
  int m0 = blockIdx.y * 128, n0 = blockIdx.x * 128;

  const unsigned short* asrc[4];
  const unsigned short* bsrc[4];
  unsigned ldsoff[4];
#pragma unroll
  for (int j = 0; j < 4; j++) {
    int c = tid + j * 256;
    int r = c >> 3;
    int cc = (c & 7) ^ (r & 7);
    ldsoff[j] = (unsigned)c * 8;
    int ma = m0 + r; if (ma > M - 1) ma = M - 1;
    asrc[j] = A + remap_row<REMAP>(ma) * K + cc * 8;
    bsrc[j] = Bw + (long)(n0 + r) * K + cc * 8;
  }

  f32x4 acc[4][4] = {};

  for (int kt = 0; kt < K; kt += 64) {
#pragma unroll
    for (int j = 0; j < 4; j++) {
      gload16(asrc[j] + kt, &At[ldsoff[j]]);
      gload16(bsrc[j] + kt, &Bt[ldsoff[j]]);
    }
    __syncthreads();
#pragma unroll
    for (int ks = 0; ks < 2; ks++) {
      bf16x8 af[4], bfr[4];
#pragma unroll
      for (int i = 0; i < 4; i++) {
        int ra = wm * 64 + i * 16 + l15;
        int ca = (ks * 64 + hi * 16) ^ ((ra & 7) << 4);
        af[i] = *(const bf16x8*)((const char*)At + ra * 128 + ca);
        int rb = wn * 64 + i * 16 + l15;
        int cb = (ks * 64 + hi * 16) ^ ((rb & 7) << 4);
        bfr[i] = *(const bf16x8*)((const char*)Bt + rb * 128 + cb);
      }
#pragma unroll
      for (int i = 0; i < 4; i++)
#pragma unroll
        for (int j = 0; j < 4; j++)
          acc[i][j] = MFMA_BF16(af[i], bfr[j], acc[i][j], 0, 0, 0);
    }
    __syncthreads();
  }

#pragma unroll
  for (int j = 0; j < 4; j++) {
    int n = n0 + wn * 64 + j * 16 + l15;
    float bv = 0.f;
    if (PROJ) bv = bias[n];
#pragma unroll
    for (int i = 0; i < 4; i++) {
      int mb = m0 + wm * 64 + i * 16 + hi * 4;
#pragma unroll
      for (int r = 0; r < 4; r++) {
        int m = mb + r;
        if (m < M) {
          if (PROJ)
            ((float*)Cout)[remap_row<REMAP>(m) * N + n] = acc[i][j][r] + bv;
          else
            ((unsigned short*)Cout)[(long)m * N + n] = f2bf(acc[i][j][r]);
        }
      }
    }
  }
}

// ---- non-act attention: one block per (h, g, b); 4 waves, each owns 64 q rows ----
__global__ void __launch_bounds__(256) attn_non(const unsigned short* __restrict__ qkv,
                                                unsigned short* __restrict__ o) {
  int h = blockIdx.x, g = blockIdx.y, b = blockIdx.z;
  __shared__ unsigned short K_s[128 * 104];
  __shared__ unsigned short V_s[80 * 136];
  __shared__ unsigned short P_s[16 * 16 * 40];
  int tid = threadIdx.x, lane = tid & 63, wid = tid >> 6;
  int l15 = lane & 15, hi = lane >> 4;
  const long base = (long)((b * 3 + g) * 256) * 3456;
  const float SC2 = 0.11785113019775793f * 1.4426950408889634f;

  bf16x8 qf[4][3];
#pragma unroll
  for (int qt = 0; qt < 4; qt++)
#pragma unroll
    for (int ds = 0; ds < 3; ds++) {
      int q = wid * 64 + qt * 16 + l15;
      int d = ds * 32 + hi * 8;
      if (d < 72)
        qf[qt][ds] = *(const bf16x8*)(qkv + base + (long)q * 3456 + h * 72 + d);
      else {
        u16x8 z = {0, 0, 0, 0, 0, 0, 0, 0};
        qf[qt][ds] = __builtin_bit_cast(bf16x8, z);
      }
    }

  f32x4 ot[5][4] = {};
  float lsum[4] = {0.f, 0.f, 0.f, 0.f};

  for (int c0 = 0; c0 < 256; c0 += 128) {
    {
      int r = tid >> 1, hf = tid & 1;
      const unsigned short* src = qkv + base + (long)(c0 + r) * 3456 + (16 + h) * 72 + hf * 48;
      unsigned short* dst = &K_s[r * 104 + hf * 48];
#pragma unroll
      for (int j = 0; j < 6; j++) {
        int col = hf * 48 + j * 8;
        u16x8 v = {0, 0, 0, 0, 0, 0, 0, 0};
        if (col < 72) v = *(const u16x8*)(src + j * 8);
        *(u16x8*)(dst + j * 8) = v;
      }
    }
    if (tid < 128) {
      const unsigned short* src = qkv + base + (long)(c0 + tid) * 3456 + (32 + h) * 72;
      u16x8 w[9];
#pragma unroll
      for (int j = 0; j < 9; j++) w[j] = *(const u16x8*)(src + j * 8);
#pragma unroll
      for (int j = 0; j < 9; j++)
#pragma unroll
        for (int e = 0; e < 8; e++) V_s[(j * 8 + e) * 136 + tid] = w[j][e];
    }
    __syncthreads();

#pragma unroll
    for (int k32 = 0; k32 < 4; k32++) {
#pragma unroll
      for (int kt = 0; kt < 2; kt++) {
        bf16x8 kf[3];
#pragma unroll
        for (int ds = 0; ds < 3; ds++)
          kf[ds] = *(const bf16x8*)((const char*)K_s +
                     ((k32 * 32 + kt * 16 + l15) * 104 + ds * 32 + hi * 8) * 2);
#pragma unroll
        for (int qt = 0; qt < 4; qt++) {
          f32x4 st = {};
#pragma unroll
          for (int ds = 0; ds < 3; ds++) st = MFMA_BF16(kf[ds], qf[qt][ds], st, 0, 0, 0);
          u16x4 pw;
#pragma unroll
          for (int r = 0; r < 4; r++) {
            float p = exp2f(st[r] * SC2);
            lsum[qt] += p;
            pw[r] = f2bf(p);
          }
          *(u16x4*)&P_s[((wid * 4 + qt) * 16 + l15) * 40 + kt * 16 + hi * 4] = pw;
        }
      }
      bf16x8 pf[4];
#pragma unroll
      for (int qt = 0; qt < 4; qt++)
        pf[qt] = *(const bf16x8*)&P_s[((wid * 4 + qt) * 16 + l15) * 40 + hi * 8];
#pragma unroll
      for (int dt = 0; dt < 5; dt++) {
        bf16x8 vf = *(const bf16x8*)&V_s[(dt * 16 + l15) * 136 + k32 * 32 + hi * 8];
#pragma unroll
        for (int qt = 0; qt < 4; qt++) ot[dt][qt] = MFMA_BF16(vf, pf[qt], ot[dt][qt], 0, 0, 0);
      }
    }
    __syncthreads();
  }

#pragma unroll
  for (int qt = 0; qt < 4; qt++) {
    float s = lsum[qt];
    s += __shfl_xor(s, 16);
    s += __shfl_xor(s, 32);
    lsum[qt] = 1.0f / s;
  }
#pragma unroll
  for (int dt = 0; dt < 5; dt++)
#pragma unroll
    for (int qt = 0; qt < 4; qt++)
#pragma unroll
      for (int r = 0; r < 4; r++) {
        int d = dt * 16 + hi * 4 + r;
        if (d < 72) {
          long row = (long)b * 825 + 57 + g * 256 + wid * 64 + qt * 16 + l15;
          o[row * 1152 + h * 72 + d] = f2bf(ot[dt][qt][r] * lsum[qt]);
        }
      }
}

// ---- act attention: one block per (h, b); 4 waves, each owns one 16-q tile (57 q) ----
__global__ void __launch_bounds__(256) attn_act(const unsigned short* __restrict__ kv,
                                                const unsigned short* __restrict__ qa,
                                                unsigned short* __restrict__ o) {
  int h = blockIdx.x, b = blockIdx.y;
  __shared__ unsigned short K_s[128 * 104];
  __shared__ unsigned short V_s[80 * 136];
  __shared__ unsigned short P_s[4 * 16 * 40];
  int tid = threadIdx.x, lane = tid & 63, wid = tid >> 6;
  int l15 = lane & 15, hi = lane >> 4;
  const float SC2 = 0.11785113019775793f * 1.4426950408889634f;
  const int LIM = 769;

  bf16x8 qf[3];
  {
    int q = wid * 16 + l15; if (q > 56) q = 56;
#pragma unroll
    for (int ds = 0; ds < 3; ds++) {
      int d = ds * 32 + hi * 8;
      if (d < 72)
        qf[ds] = *(const bf16x8*)(qa + (long)(b * 57 + q) * 1152 + h * 72 + d);
      else {
        u16x8 z = {0, 0, 0, 0, 0, 0, 0, 0};
        qf[ds] = __builtin_bit_cast(bf16x8, z);
      }
    }
  }

  f32x4 ot[5] = {};
  float lsum = 0.f;
  const long kbase = (long)b * 825 + 56;

  for (int c0 = 0; c0 < LIM; c0 += 128) {
    int valid = LIM - c0; if (valid > 128) valid = 128;
    {
      int r = tid >> 1, hf = tid & 1;
      int rr = r < valid ? r : valid - 1;
      const unsigned short* src = kv + (kbase + c0 + rr) * 2304 + h * 72 + hf * 48;
      unsigned short* dst = &K_s[r * 104 + hf * 48];
#pragma unroll
      for (int j = 0; j < 6; j++) {
        int col = hf * 48 + j * 8;
        u16x8 v = {0, 0, 0, 0, 0, 0, 0, 0};
        if (col < 72) v = *(const u16x8*)(src + j * 8);
        *(u16x8*)(dst + j * 8) = v;
      }
    }
    if (tid < 128) {
      int rr = tid < valid ? tid : valid - 1;
      const unsigned short* src = kv + (kbase + c0 + rr) * 2304 + (16 + h) * 72;
      u16x8 w[9];
#pragma unroll
      for (int j = 0; j < 9; j++) w[j] = *(const u16x8*)(src + j * 8);
#pragma unroll
      for (int j = 0; j < 9; j++)
#pragma unroll
        for (int e = 0; e < 8; e++) V_s[(j * 8 + e) * 136 + tid] = w[j][e];
    }
    __syncthreads();

#pragma unroll
    for (int k32 = 0; k32 < 4; k32++) {
#pragma unroll
      for (int kt = 0; kt < 2; kt++) {
        bf16x8 kf[3];
#pragma unroll
        for (int ds = 0; ds < 3; ds++)
          kf[ds] = *(const bf16x8*)((const char*)K_s +
                     ((k32 * 32 + kt * 16 + l15) * 104 + ds * 32 + hi * 8) * 2);
        f32x4 st = {};
#pragma unroll
        for (int ds = 0; ds < 3; ds++) st = MFMA_BF16(kf[ds], qf[ds], st, 0, 0, 0);
        u16x4 pw;
#pragma unroll
        for (int r = 0; r < 4; r++) {
          int kg = c0 + k32 * 32 + kt * 16 + hi * 4 + r;
          float p = (kg < LIM) ? exp2f(st[r] * SC2) : 0.f;
          lsum += p;
          pw[r] = f2bf(p);
        }
        *(u16x4*)&P_s[(wid * 16 + l15) * 40 + kt * 16 + hi * 4] = pw;
      }
      bf16x8 pf = *(const bf16x8*)&P_s[(wid * 16 + l15) * 40 + hi * 8];
#pragma unroll
      for (int dt = 0; dt < 5; dt++) {
        bf16x8 vf = *(const bf16x8*)&V_s[(dt * 16 + l15) * 136 + k32 * 32 + hi * 8];
        ot[dt] = MFMA_BF16(vf, pf, ot[dt], 0, 0, 0);
      }
    }
    __syncthreads();
  }

  {
    float s = lsum;
    s += __shfl_xor(s, 16);
    s += __shfl_xor(s, 32);
    lsum = 1.0f / s;
  }
  int q = wid * 16 + l15;
#pragma unroll
  for (int dt = 0; dt < 5; dt++)
#pragma unroll
    for (int r = 0; r < 4; r++) {
      int d = dt * 16 + hi * 4 + r;
      if (d < 72 && q < 57)
        o[((long)b * 825 + q) * 1152 + h * 72 + d] = f2bf(ot[dt][r] * lsum);
    }
}

extern "C" void kernel_launch(void* const* d_in, const int* in_sizes, int n_in,
                              void* d_out, int out_size, void* d_ws, size_t ws_size,
                              hipStream_t stream) {
  const float* x     = (const float*)d_in[0];
  const float* w_qkv = (const float*)d_in[1];
  const float* w_q   = (const float*)d_in[2];
  const float* w_kv  = (const float*)d_in[3];
  const float* w_pn  = (const float*)d_in[4];
  const float* b_pn  = (const float*)d_in[5];
  const float* w_pa  = (const float*)d_in[6];
  const float* b_pa  = (const float*)d_in[7];

  char* ws = (char*)d_ws;
  unsigned short* xb    = (unsigned short*)ws; ws += (size_t)26400 * 1152 * 2;
  unsigned short* wqkvb = (unsigned short*)ws; ws += (size_t)3456 * 1152 * 2;
  unsigned short* wqb   = (unsigned short*)ws; ws += (size_t)1152 * 1152 * 2;
  unsigned short* wkvb  = (unsigned short*)ws; ws += (size_t)2304 * 1152 * 2;
  unsigned short* wpnb  = (unsigned short*)ws; ws += (size_t)1152 * 1152 * 2;
  unsigned short* wpab  = (unsigned short*)ws; ws += (size_t)1152 * 1152 * 2;
  unsigned short* qkvw  = (unsigned short*)ws; ws += (size_t)24576 * 3456 * 2;
  unsigned short* kvw   = (unsigned short*)ws; ws += (size_t)26400 * 2304 * 2;
  unsigned short* qw    = (unsigned short*)ws; ws += (size_t)1824 * 1152 * 2;
  unsigned short* attnw = (unsigned short*)ws; ws += (size_t)26400 * 1152 * 2;

  auto cast = [&](const float* src, unsigned short* dst, long n) {
    int n8 = (int)(n / 8);
    cast_bf16_kernel<<<(n8 + 255) / 256, 256, 0, stream>>>(src, dst, n8);
  };
  cast(x,     xb,    26400L * 1152);
  cast(w_qkv, wqkvb, 3456L * 1152);
  cast(w_q,   wqb,   1152L * 1152);
  cast(w_kv,  wkvb,  2304L * 1152);
  cast(w_pn,  wpnb,  1152L * 1152);
  cast(w_pa,  wpab,  1152L * 1152);

  // qkv_non = x[:,57:] @ w_qkv^T   (M=24576, N=3456): 96 x 14 tiles
  gemm256<1, false><<<dim3(14, 96), 512, 0, stream>>>(xb, wqkvb, qkvw, nullptr, 24576, 3456);
  // kv_act = x @ w_kv^T            (M=26400, N=2304): 104 x 9 tiles
  gemm256<0, false><<<dim3(9, 104), 512, 0, stream>>>(xb, wkvb, kvw, nullptr, 26400, 2304);
  // q_act = x[:,:57] @ w_q^T       (M=1824, N=1152) - small, 128-tile path
  gemm_bt<2, false><<<dim3(9, 15), 256, 0, stream>>>(xb, wqb, qw, nullptr, 1824, 1152);

  attn_non<<<dim3(16, 3, 32), 256, 0, stream>>>(qkvw, attnw);
  attn_act<<<dim3(16, 32), 256, 0, stream>>>(kvw, qw, attnw);

  // projections into d_out (fp32), rows remapped to [act | non] layout
  gemm256<1, true><<<dim3(5, 96), 512, 0, stream>>>(attnw, wpnb, d_out, b_pn, 24576, 1152);
  gemm_bt<2, true><<<dim3(9, 15), 256, 0, stream>>>(attnw, wpab, d_out, b_pa, 1824, 1152);
}

// Round 3
// 825.222 us; speedup vs baseline: 1.0743x; 1.0472x over previous
//
#include <hip/hip_runtime.h>

typedef __attribute__((ext_vector_type(8))) __bf16 bf16x8;
typedef __attribute__((ext_vector_type(4))) float f32x4;
typedef __attribute__((ext_vector_type(4))) unsigned short u16x4;
typedef __attribute__((ext_vector_type(8))) unsigned short u16x8;

#define MFMA_BF16 __builtin_amdgcn_mfma_f32_16x16x32_bf16

__device__ __forceinline__ unsigned short f2bf(float f) {
  union { float f; unsigned u; } v; v.f = f;
  unsigned r = v.u + 0x7FFFu + ((v.u >> 16) & 1u);
  return (unsigned short)(r >> 16);
}

__device__ __forceinline__ void gload16(const void* g, void* l) {
  __builtin_amdgcn_global_load_lds(
      (const __attribute__((address_space(1))) unsigned int*)g,
      (__attribute__((address_space(3))) unsigned int*)l, 16, 0, 0);
}

__global__ void __launch_bounds__(256) cast_bf16_kernel(const float* __restrict__ in,
                                                        unsigned short* __restrict__ out,
                                                        int n8) {
  int i = blockIdx.x * 256 + threadIdx.x;
  if (i >= n8) return;
  long base = (long)i * 8;
  float4 a = *(const float4*)(in + base);
  float4 b = *(const float4*)(in + base + 4);
  u16x8 o;
  o[0] = f2bf(a.x); o[1] = f2bf(a.y); o[2] = f2bf(a.z); o[3] = f2bf(a.w);
  o[4] = f2bf(b.x); o[5] = f2bf(b.y); o[6] = f2bf(b.z); o[7] = f2bf(b.w);
  *(u16x8*)(out + base) = o;
}

// row remapping: 0 = identity, 1 = b*825 + 57 + (m % 768), 2 = b*825 + (m % 57)
template <int REMAP>
__device__ __forceinline__ long remap_row(int m) {
  if (REMAP == 1) { int b = m / 768; return (long)b * 825 + 57 + (m - b * 768); }
  if (REMAP == 2) { int b = m / 57;  return (long)b * 825 + (m - b * 57); }
  return m;
}

// ============ 256x256 tile, BK=64, 8-wave, 4-phase/K-tile counted-vmcnt GEMM ============
// C[M,N] = A[M,1152] @ B[N,1152]^T. LDS: A-ring 4 slots + B-ring 4 slots, slot=[256][32] bf16.
// Bank swizzle: logical k-chunk c stored at physical chunk (c + (row>>1))&3 so that 8
// consecutive rows at a fixed chunk hit 8 distinct 16B bank-quads (2-way over 16 = free).
template <int REMAP, bool PROJ>
__global__ void __launch_bounds__(512, 2) gemm256(const unsigned short* __restrict__ A,
                                                  const unsigned short* __restrict__ Bw,
                                                  void* __restrict__ Cout,
                                                  const float* __restrict__ bias,
                                                  int M, int N) {
  const int K = 1152;
  __shared__ unsigned short L[65536];  // 128 KiB: A slots [0,32768), B slots [32768,65536)
  unsigned short* Al = L;
  unsigned short* Bl = L + 32768;
  int tid = threadIdx.x;
  int lane = tid & 63;
  int wid = tid >> 6;
  int l15 = lane & 15, hi = lane >> 4;
  int wm = wid >> 2, wn = wid & 3;

  // bijective XCD swizzle (all grids used are divisible by 8)
  int gx = gridDim.x;
  int nwg = gx * gridDim.y;
  int orig = blockIdx.y * gx + blockIdx.x;
  int q8 = nwg >> 3, r8 = nwg & 7;
  int xcd = orig & 7, off = orig >> 3;
  int wgid = (xcd < r8 ? xcd * (q8 + 1) : r8 * (q8 + 1) + (xcd - r8) * q8) + off;
  int bn = wgid % gx, bm = wgid / gx;
  int m0 = bm * 256, n0 = bn * 256;

  // staging geometry: thread stages 16B at slot-bytes tid*16 and tid*16+8192
  int rlo = tid >> 2;                      // 0..127 (row within half)
  int cg = ((tid & 3) - (tid >> 3)) & 3;   // global k-chunk for physical chunk (tid&3)
  int ma0 = m0 + rlo;       if (ma0 > M - 1) ma0 = M - 1;
  int ma1 = m0 + rlo + 128; if (ma1 > M - 1) ma1 = M - 1;
  const unsigned short* aptr0 = A + remap_row<REMAP>(ma0) * K + cg * 8;
  const unsigned short* aptr1 = A + remap_row<REMAP>(ma1) * K + cg * 8;
  int nb0 = n0 + rlo;       if (nb0 > N - 1) nb0 = N - 1;
  int nb1 = n0 + rlo + 128; if (nb1 > N - 1) nb1 = N - 1;
  const unsigned short* bptr0 = Bw + (long)nb0 * K + cg * 8;
  const unsigned short* bptr1 = Bw + (long)nb1 * K + cg * 8;
  unsigned ldst = (unsigned)tid * 8;  // element offset within slot

  auto stageA = [&](int tt, int hh) {
    int koff = tt * 64 + hh * 32;
    unsigned short* d = Al + (((2 * tt + hh) & 3) << 13) + ldst;
    gload16(aptr0 + koff, d);
    gload16(aptr1 + koff, d + 4096);
  };
  auto stageB = [&](int tt, int hh) {
    int koff = tt * 64 + hh * 32;
    unsigned short* d = Bl + (((2 * tt + hh) & 3) << 13) + ldst;
    gload16(bptr0 + koff, d);
    gload16(bptr1 + koff, d + 4096);
  };

  // prologue: ht[0..5] = A(0,0) B(0,0) A(0,1) B(0,1) A(1,0) B(1,0)
  stageA(0, 0); stageB(0, 0); stageA(0, 1); stageB(0, 1);
  __builtin_amdgcn_sched_barrier(0);
  stageA(1, 0); stageB(1, 0);
  __builtin_amdgcn_sched_barrier(0);
  asm volatile("s_waitcnt vmcnt(4)" ::: "memory");  // K-tile 0 landed
  __builtin_amdgcn_s_barrier();
  __builtin_amdgcn_sched_barrier(0);

  f32x4 acc[8][4] = {};
  bf16x8 bfr[4];
  const int cl = (hi + (l15 >> 1)) & 3;  // physical chunk for logical chunk hi (all rows read)

  for (int t = 0; t < 18; ++t) {
#pragma unroll
    for (int q = 0; q < 4; ++q) {
      const int h = q >> 1, mh = q & 1;
      const int slot = (2 * t + h) & 3;
      bf16x8 af[4];
#pragma unroll
      for (int f = 0; f < 4; ++f) {
        int row = wm * 128 + mh * 64 + f * 16 + l15;
        af[f] = *(const bf16x8*)(Al + (slot << 13) + row * 32 + cl * 8);
      }
      if (mh == 0) {
#pragma unroll
        for (int f = 0; f < 4; ++f) {
          int row = wn * 64 + f * 16 + l15;
          bfr[f] = *(const bf16x8*)(Bl + (slot << 13) + row * 32 + cl * 8);
        }
      }
      // stage ht[p+6]
      if (q == 0)      { if (t + 1 < 18) stageA(t + 1, 1); }
      else if (q == 1) { if (t + 1 < 18) stageB(t + 1, 1); }
      else if (q == 2) { if (t + 2 < 18) stageA(t + 2, 0); }
      else             { if (t + 2 < 18) stageB(t + 2, 0); }
      __builtin_amdgcn_s_barrier();
      __builtin_amdgcn_s_setprio(1);
#pragma unroll
      for (int fm = 0; fm < 4; ++fm)
#pragma unroll
        for (int fn = 0; fn < 4; ++fn)
          acc[mh * 4 + fm][fn] = MFMA_BF16(af[fm], bfr[fn], acc[mh * 4 + fm][fn], 0, 0, 0);
      __builtin_amdgcn_s_setprio(0);
      if (q == 3) {
        if (t < 16) asm volatile("s_waitcnt vmcnt(4)" ::: "memory");
        else        asm volatile("s_waitcnt vmcnt(0)" ::: "memory");
      }
      __builtin_amdgcn_sched_barrier(0);
      __builtin_amdgcn_s_barrier();
      __builtin_amdgcn_sched_barrier(0);
    }
  }

#pragma unroll
  for (int fn = 0; fn < 4; ++fn) {
    int n = n0 + wn * 64 + fn * 16 + l15;
    if (n < N) {
      float bv = 0.f;
      if (PROJ) bv = bias[n];
#pragma unroll
      for (int a = 0; a < 8; ++a) {
        int mb = m0 + wm * 128 + (a >> 2) * 64 + (a & 3) * 16 + hi * 4;
#pragma unroll
        for (int r = 0; r < 4; ++r) {
          int m = mb + r;
          if (m < M) {
            if (PROJ)
              ((float*)Cout)[remap_row<REMAP>(m) * N + n] = acc[a][fn][r] + bv;
            else
              ((unsigned short*)Cout)[(long)m * N + n] = f2bf(acc[a][fn][r]);
          }
        }
      }
    }
  }
}

// ============ 128x128 tile GEMM (kept for the two small GEMMs) ============
template <int REMAP, bool PROJ>
__global__ void __launch_bounds__(256) gemm_bt(const unsigned short* __restrict__ A,
                                               const unsigned short* __restrict__ Bw,
                                               void* __restrict__ Cout,
                                               const float* __restrict__ bias,
                                               int M, int N) {
  const int K = 1152;
  __shared__ unsigned short At[128 * 64];
  __shared__ unsigned short Bt[128 * 64];
  int tid = threadIdx.x;
  int lane = tid & 63, wid = tid >> 6;
  int l15 = lane & 15, hi = lane >> 4;
  int wm = wid >> 1, wn = wid & 1;
  int m0 = blockIdx.y * 128, n0 = blockIdx.x * 128;

  const unsigned short* asrc[4];
  const unsigned short* bsrc[4];
  unsigned ldsoff[4];
#pragma unroll
  for (int j = 0; j < 4; j++) {
    int c = tid + j * 256;
    int r = c >> 3;
    int cc = (c & 7) ^ (r & 7);
    ldsoff[j] = (unsigned)c * 8;
    int ma = m0 + r; if (ma > M - 1) ma = M - 1;
    asrc[j] = A + remap_row<REMAP>(ma) * K + cc * 8;
    bsrc[j] = Bw + (long)(n0 + r) * K + cc * 8;
  }

  f32x4 acc[4][4] = {};

  for (int kt = 0; kt < K; kt += 64) {
#pragma unroll
    for (int j = 0; j < 4; j++) {
      gload16(asrc[j] + kt, &At[ldsoff[j]]);
      gload16(bsrc[j] + kt, &Bt[ldsoff[j]]);
    }
    __syncthreads();
#pragma unroll
    for (int ks = 0; ks < 2; ks++) {
      bf16x8 af[4], bfr[4];
#pragma unroll
      for (int i = 0; i < 4; i++) {
        int ra = wm * 64 + i * 16 + l15;
        int ca = (ks * 64 + hi * 16) ^ ((ra & 7) << 4);
        af[i] = *(const bf16x8*)((const char*)At + ra * 128 + ca);
        int rb = wn * 64 + i * 16 + l15;
        int cb = (ks * 64 + hi * 16) ^ ((rb & 7) << 4);
        bfr[i] = *(const bf16x8*)((const char*)Bt + rb * 128 + cb);
      }
#pragma unroll
      for (int i = 0; i < 4; i++)
#pragma unroll
        for (int j = 0; j < 4; j++)
          acc[i][j] = MFMA_BF16(af[i], bfr[j], acc[i][j], 0, 0, 0);
    }
    __syncthreads();
  }

#pragma unroll
  for (int j = 0; j < 4; j++) {
    int n = n0 + wn * 64 + j * 16 + l15;
    float bv = 0.f;
    if (PROJ) bv = bias[n];
#pragma unroll
    for (int i = 0; i < 4; i++) {
      int mb = m0 + wm * 64 + i * 16 + hi * 4;
#pragma unroll
      for (int r = 0; r < 4; r++) {
        int m = mb + r;
        if (m < M) {
          if (PROJ)
            ((float*)Cout)[remap_row<REMAP>(m) * N + n] = acc[i][j][r] + bv;
          else
            ((unsigned short*)Cout)[(long)m * N + n] = f2bf(acc[i][j][r]);
        }
      }
    }
  }
}

// ---- non-act attention: one block per (h, g, b); 4 waves, each owns 64 q rows ----
__global__ void __launch_bounds__(256) attn_non(const unsigned short* __restrict__ qkv,
                                                unsigned short* __restrict__ o) {
  int h = blockIdx.x, g = blockIdx.y, b = blockIdx.z;
  __shared__ unsigned short K_s[128 * 104];
  __shared__ unsigned short V_s[80 * 136];
  __shared__ unsigned short P_s[16 * 16 * 40];
  int tid = threadIdx.x, lane = tid & 63, wid = tid >> 6;
  int l15 = lane & 15, hi = lane >> 4;
  const long base = (long)((b * 3 + g) * 256) * 3456;
  const float SC2 = 0.11785113019775793f * 1.4426950408889634f;

  bf16x8 qf[4][3];
#pragma unroll
  for (int qt = 0; qt < 4; qt++)
#pragma unroll
    for (int ds = 0; ds < 3; ds++) {
      int q = wid * 64 + qt * 16 + l15;
      int d = ds * 32 + hi * 8;
      if (d < 72)
        qf[qt][ds] = *(const bf16x8*)(qkv + base + (long)q * 3456 + h * 72 + d);
      else {
        u16x8 z = {0, 0, 0, 0, 0, 0, 0, 0};
        qf[qt][ds] = __builtin_bit_cast(bf16x8, z);
      }
    }

  f32x4 ot[5][4] = {};
  float lsum[4] = {0.f, 0.f, 0.f, 0.f};

  for (int c0 = 0; c0 < 256; c0 += 128) {
    {
      int r = tid >> 1, hf = tid & 1;
      const unsigned short* src = qkv + base + (long)(c0 + r) * 3456 + (16 + h) * 72 + hf * 48;
      unsigned short* dst = &K_s[r * 104 + hf * 48];
#pragma unroll
      for (int j = 0; j < 6; j++) {
        int col = hf * 48 + j * 8;
        u16x8 v = {0, 0, 0, 0, 0, 0, 0, 0};
        if (col < 72) v = *(const u16x8*)(src + j * 8);
        *(u16x8*)(dst + j * 8) = v;
      }
    }
    if (tid < 128) {
      const unsigned short* src = qkv + base + (long)(c0 + tid) * 3456 + (32 + h) * 72;
      u16x8 w[9];
#pragma unroll
      for (int j = 0; j < 9; j++) w[j] = *(const u16x8*)(src + j * 8);
#pragma unroll
      for (int j = 0; j < 9; j++)
#pragma unroll
        for (int e = 0; e < 8; e++) V_s[(j * 8 + e) * 136 + tid] = w[j][e];
    }
    __syncthreads();

#pragma unroll
    for (int k32 = 0; k32 < 4; k32++) {
#pragma unroll
      for (int kt = 0; kt < 2; kt++) {
        bf16x8 kf[3];
#pragma unroll
        for (int ds = 0; ds < 3; ds++)
          kf[ds] = *(const bf16x8*)((const char*)K_s +
                     ((k32 * 32 + kt * 16 + l15) * 104 + ds * 32 + hi * 8) * 2);
#pragma unroll
        for (int qt = 0; qt < 4; qt++) {
          f32x4 st = {};
#pragma unroll
          for (int ds = 0; ds < 3; ds++) st = MFMA_BF16(kf[ds], qf[qt][ds], st, 0, 0, 0);
          u16x4 pw;
#pragma unroll
          for (int r = 0; r < 4; r++) {
            float p = exp2f(st[r] * SC2);
            lsum[qt] += p;
            pw[r] = f2bf(p);
          }
          *(u16x4*)&P_s[((wid * 4 + qt) * 16 + l15) * 40 + kt * 16 + hi * 4] = pw;
        }
      }
      bf16x8 pf[4];
#pragma unroll
      for (int qt = 0; qt < 4; qt++)
        pf[qt] = *(const bf16x8*)&P_s[((wid * 4 + qt) * 16 + l15) * 40 + hi * 8];
#pragma unroll
      for (int dt = 0; dt < 5; dt++) {
        bf16x8 vf = *(const bf16x8*)&V_s[(dt * 16 + l15) * 136 + k32 * 32 + hi * 8];
#pragma unroll
        for (int qt = 0; qt < 4; qt++) ot[dt][qt] = MFMA_BF16(vf, pf[qt], ot[dt][qt], 0, 0, 0);
      }
    }
    __syncthreads();
  }

#pragma unroll
  for (int qt = 0; qt < 4; qt++) {
    float s = lsum[qt];
    s += __shfl_xor(s, 16);
    s += __shfl_xor(s, 32);
    lsum[qt] = 1.0f / s;
  }
#pragma unroll
  for (int dt = 0; dt < 5; dt++)
#pragma unroll
    for (int qt = 0; qt < 4; qt++)
#pragma unroll
      for (int r = 0; r < 4; r++) {
        int d = dt * 16 + hi * 4 + r;
        if (d < 72) {
          long row = (long)b * 825 + 57 + g * 256 + wid * 64 + qt * 16 + l15;
          o[row * 1152 + h * 72 + d] = f2bf(ot[dt][qt][r] * lsum[qt]);
        }
      }
}

// ---- act attention: one block per (h, b); 4 waves, each owns one 16-q tile (57 q) ----
__global__ void __launch_bounds__(256) attn_act(const unsigned short* __restrict__ kv,
                                                const unsigned short* __restrict__ qa,
                                                unsigned short* __restrict__ o) {
  int h = blockIdx.x, b = blockIdx.y;
  __shared__ unsigned short K_s[128 * 104];
  __shared__ unsigned short V_s[80 * 136];
  __shared__ unsigned short P_s[4 * 16 * 40];
  int tid = threadIdx.x, lane = tid & 63, wid = tid >> 6;
  int l15 = lane & 15, hi = lane >> 4;
  const float SC2 = 0.11785113019775793f * 1.4426950408889634f;
  const int LIM = 769;

  bf16x8 qf[3];
  {
    int q = wid * 16 + l15; if (q > 56) q = 56;
#pragma unroll
    for (int ds = 0; ds < 3; ds++) {
      int d = ds * 32 + hi * 8;
      if (d < 72)
        qf[ds] = *(const bf16x8*)(qa + (long)(b * 57 + q) * 1152 + h * 72 + d);
      else {
        u16x8 z = {0, 0, 0, 0, 0, 0, 0, 0};
        qf[ds] = __builtin_bit_cast(bf16x8, z);
      }
    }
  }

  f32x4 ot[5] = {};
  float lsum = 0.f;
  const long kbase = (long)b * 825 + 56;

  for (int c0 = 0; c0 < LIM; c0 += 128) {
    int valid = LIM - c0; if (valid > 128) valid = 128;
    {
      int r = tid >> 1, hf = tid & 1;
      int rr = r < valid ? r : valid - 1;
      const unsigned short* src = kv + (kbase + c0 + rr) * 2304 + h * 72 + hf * 48;
      unsigned short* dst = &K_s[r * 104 + hf * 48];
#pragma unroll
      for (int j = 0; j < 6; j++) {
        int col = hf * 48 + j * 8;
        u16x8 v = {0, 0, 0, 0, 0, 0, 0, 0};
        if (col < 72) v = *(const u16x8*)(src + j * 8);
        *(u16x8*)(dst + j * 8) = v;
      }
    }
    if (tid < 128) {
      int rr = tid < valid ? tid : valid - 1;
      const unsigned short* src = kv + (kbase + c0 + rr) * 2304 + (16 + h) * 72;
      u16x8 w[9];
#pragma unroll
      for (int j = 0; j < 9; j++) w[j] = *(const u16x8*)(src + j * 8);
#pragma unroll
      for (int j = 0; j < 9; j++)
#pragma unroll
        for (int e = 0; e < 8; e++) V_s[(j * 8 + e) * 136 + tid] = w[j][e];
    }
    __syncthreads();

#pragma unroll
    for (int k32 = 0; k32 < 4; k32++) {
#pragma unroll
      for (int kt = 0; kt < 2; kt++) {
        bf16x8 kf[3];
#pragma unroll
        for (int ds = 0; ds < 3; ds++)
          kf[ds] = *(const bf16x8*)((const char*)K_s +
                     ((k32 * 32 + kt * 16 + l15) * 104 + ds * 32 + hi * 8) * 2);
        f32x4 st = {};
#pragma unroll
        for (int ds = 0; ds < 3; ds++) st = MFMA_BF16(kf[ds], qf[ds], st, 0, 0, 0);
        u16x4 pw;
#pragma unroll
        for (int r = 0; r < 4; r++) {
          int kg = c0 + k32 * 32 + kt * 16 + hi * 4 + r;
          float p = (kg < LIM) ? exp2f(st[r] * SC2) : 0.f;
          lsum += p;
          pw[r] = f2bf(p);
        }
        *(u16x4*)&P_s[(wid * 16 + l15) * 40 + kt * 16 + hi * 4] = pw;
      }
      bf16x8 pf = *(const bf16x8*)&P_s[(wid * 16 + l15) * 40 + hi * 8];
#pragma unroll
      for (int dt = 0; dt < 5; dt++) {
        bf16x8 vf = *(const bf16x8*)&V_s[(dt * 16 + l15) * 136 + k32 * 32 + hi * 8];
        ot[dt] = MFMA_BF16(vf, pf, ot[dt], 0, 0, 0);
      }
    }
    __syncthreads();
  }

  {
    float s = lsum;
    s += __shfl_xor(s, 16);
    s += __shfl_xor(s, 32);
    lsum = 1.0f / s;
  }
  int q = wid * 16 + l15;
#pragma unroll
  for (int dt = 0; dt < 5; dt++)
#pragma unroll
    for (int r = 0; r < 4; r++) {
      int d = dt * 16 + hi * 4 + r;
      if (d < 72 && q < 57)
        o[((long)b * 825 + q) * 1152 + h * 72 + d] = f2bf(ot[dt][r] * lsum);
    }
}

extern "C" void kernel_launch(void* const* d_in, const int* in_sizes, int n_in,
                              void* d_out, int out_size, void* d_ws, size_t ws_size,
                              hipStream_t stream) {
  const float* x     = (const float*)d_in[0];
  const float* w_qkv = (const float*)d_in[1];
  const float* w_q   = (const float*)d_in[2];
  const float* w_kv  = (const float*)d_in[3];
  const float* w_pn  = (const float*)d_in[4];
  const float* b_pn  = (const float*)d_in[5];
  const float* w_pa  = (const float*)d_in[6];
  const float* b_pa  = (const float*)d_in[7];

  char* ws = (char*)d_ws;
  unsigned short* xb    = (unsigned short*)ws; ws += (size_t)26400 * 1152 * 2;
  unsigned short* wqkvb = (unsigned short*)ws; ws += (size_t)3456 * 1152 * 2;
  unsigned short* wqb   = (unsigned short*)ws; ws += (size_t)1152 * 1152 * 2;
  unsigned short* wkvb  = (unsigned short*)ws; ws += (size_t)2304 * 1152 * 2;
  unsigned short* wpnb  = (unsigned short*)ws; ws += (size_t)1152 * 1152 * 2;
  unsigned short* wpab  = (unsigned short*)ws; ws += (size_t)1152 * 1152 * 2;
  unsigned short* qkvw  = (unsigned short*)ws; ws += (size_t)24576 * 3456 * 2;
  unsigned short* kvw   = (unsigned short*)ws; ws += (size_t)26400 * 2304 * 2;
  unsigned short* qw    = (unsigned short*)ws; ws += (size_t)1824 * 1152 * 2;
  unsigned short* attnw = (unsigned short*)ws; ws += (size_t)26400 * 1152 * 2;

  auto cast = [&](const float* src, unsigned short* dst, long n) {
    int n8 = (int)(n / 8);
    cast_bf16_kernel<<<(n8 + 255) / 256, 256, 0, stream>>>(src, dst, n8);
  };
  cast(x,     xb,    26400L * 1152);
  cast(w_qkv, wqkvb, 3456L * 1152);
  cast(w_q,   wqb,   1152L * 1152);
  cast(w_kv,  wkvb,  2304L * 1152);
  cast(w_pn,  wpnb,  1152L * 1152);
  cast(w_pa,  wpab,  1152L * 1152);

  // qkv_non = x[:,57:] @ w_qkv^T   (M=24576, N=3456): 96 x 14 tiles
  gemm256<1, false><<<dim3(14, 96), 512, 0, stream>>>(xb, wqkvb, qkvw, nullptr, 24576, 3456);
  // kv_act = x @ w_kv^T            (M=26400, N=2304): 104 x 9 tiles
  gemm256<0, false><<<dim3(9, 104), 512, 0, stream>>>(xb, wkvb, kvw, nullptr, 26400, 2304);
  // q_act = x[:,:57] @ w_q^T       (M=1824, N=1152) - small, 128-tile path
  gemm_bt<2, false><<<dim3(9, 15), 256, 0, stream>>>(xb, wqb, qw, nullptr, 1824, 1152);

  attn_non<<<dim3(16, 3, 32), 256, 0, stream>>>(qkvw, attnw);
  attn_act<<<dim3(16, 32), 256, 0, stream>>>(kvw, qw, attnw);

  // projections into d_out (fp32), rows remapped to [act | non] layout
  gemm256<1, true><<<dim3(5, 96), 512, 0, stream>>>(attnw, wpnb, d_out, b_pn, 24576, 1152);
  gemm_bt<2, true><<<dim3(9, 15), 256, 0, stream>>>(attnw, wpab, d_out, b_pa, 1824, 1152);
}

// Round 4
// 813.053 us; speedup vs baseline: 1.0903x; 1.0150x over previous
//
#include <hip/hip_runtime.h>

typedef __attribute__((ext_vector_type(8))) __bf16 bf16x8;
typedef __attribute__((ext_vector_type(4))) float f32x4;
typedef __attribute__((ext_vector_type(4))) unsigned short u16x4;
typedef __attribute__((ext_vector_type(8))) unsigned short u16x8;

#define MFMA_BF16 __builtin_amdgcn_mfma_f32_16x16x32_bf16

__device__ __forceinline__ unsigned short f2bf(float f) {
  union { float f; unsigned u; } v; v.f = f;
  unsigned r = v.u + 0x7FFFu + ((v.u >> 16) & 1u);
  return (unsigned short)(r >> 16);
}

__device__ __forceinline__ void gload16(const void* g, void* l) {
  __builtin_amdgcn_global_load_lds(
      (const __attribute__((address_space(1))) unsigned int*)g,
      (__attribute__((address_space(3))) unsigned int*)l, 16, 0, 0);
}

__global__ void __launch_bounds__(256) cast_bf16_kernel(const float* __restrict__ in,
                                                        unsigned short* __restrict__ out,
                                                        int n8) {
  int i = blockIdx.x * 256 + threadIdx.x;
  if (i >= n8) return;
  long base = (long)i * 8;
  float4 a = *(const float4*)(in + base);
  float4 b = *(const float4*)(in + base + 4);
  u16x8 o;
  o[0] = f2bf(a.x); o[1] = f2bf(a.y); o[2] = f2bf(a.z); o[3] = f2bf(a.w);
  o[4] = f2bf(b.x); o[5] = f2bf(b.y); o[6] = f2bf(b.z); o[7] = f2bf(b.w);
  *(u16x8*)(out + base) = o;
}

// row remapping: 0 = identity, 1 = b*825 + 57 + (m % 768), 2 = b*825 + (m % 57)
template <int REMAP>
__device__ __forceinline__ long remap_row(int m) {
  if (REMAP == 1) { int b = m / 768; return (long)b * 825 + 57 + (m - b * 768); }
  if (REMAP == 2) { int b = m / 57;  return (long)b * 825 + (m - b * 57); }
  return m;
}

// ============ 256x256 tile, BK=64, 8-wave, 4-phase/K-tile counted-vmcnt GEMM ============
// Fully unrolled t-loop: slot indices / mh / koff are compile-time, so every ds_read is
// base-VGPR + imm-offset and every stage folds koff into the 13-bit global offset.
template <int REMAP, bool PROJ>
__global__ void __launch_bounds__(512, 2) gemm256(const unsigned short* __restrict__ A,
                                                  const unsigned short* __restrict__ Bw,
                                                  void* __restrict__ Cout,
                                                  const float* __restrict__ bias,
                                                  int M, int N) {
  const int K = 1152;
  const int NT = 18;  // K / 64
  __shared__ unsigned short L[65536];  // 128 KiB: A slots [0,32768), B slots [32768,65536)
  unsigned short* Al = L;
  unsigned short* Bl = L + 32768;
  int tid = threadIdx.x;
  int lane = tid & 63;
  int wid = tid >> 6;
  int l15 = lane & 15, hi = lane >> 4;
  int wm = wid >> 2, wn = wid & 3;

  // bijective XCD swizzle (all grids used are divisible by 8)
  int gx = gridDim.x;
  int nwg = gx * gridDim.y;
  int orig = blockIdx.y * gx + blockIdx.x;
  int q8 = nwg >> 3, r8 = nwg & 7;
  int xcd = orig & 7, off = orig >> 3;
  int wgid = (xcd < r8 ? xcd * (q8 + 1) : r8 * (q8 + 1) + (xcd - r8) * q8) + off;
  int bn = wgid % gx, bm = wgid / gx;
  int m0 = bm * 256, n0 = bn * 256;

  // staging geometry: thread stages 16B at slot-bytes tid*16 and tid*16+8192
  int rlo = tid >> 2;                      // 0..127 (row within half)
  int cg = ((tid & 3) - (tid >> 3)) & 3;   // global k-chunk for physical chunk (tid&3)
  int ma0 = m0 + rlo;       if (ma0 > M - 1) ma0 = M - 1;
  int ma1 = m0 + rlo + 128; if (ma1 > M - 1) ma1 = M - 1;
  const unsigned short* aptr0 = A + remap_row<REMAP>(ma0) * K + cg * 8;
  const unsigned short* aptr1 = A + remap_row<REMAP>(ma1) * K + cg * 8;
  int nb0 = n0 + rlo;       if (nb0 > N - 1) nb0 = N - 1;
  int nb1 = n0 + rlo + 128; if (nb1 > N - 1) nb1 = N - 1;
  const unsigned short* bptr0 = Bw + (long)nb0 * K + cg * 8;
  const unsigned short* bptr1 = Bw + (long)nb1 * K + cg * 8;
  unsigned ldst = (unsigned)tid * 8;  // element offset within slot

  // LDS stage destinations (element offsets; slot const folds per unrolled site)
  unsigned short* Ad = Al + ldst;
  unsigned short* Bd = Bl + ldst;

  // hoisted ds_read base addresses (slot and mh become immediate offsets)
  const int cl = (hi + (l15 >> 1)) & 3;  // physical chunk for logical chunk hi
  const unsigned short* arb[4];
  const unsigned short* brb[4];
#pragma unroll
  for (int f = 0; f < 4; ++f) {
    arb[f] = Al + (wm * 128 + f * 16 + l15) * 32 + cl * 8;
    brb[f] = Bl + (wn * 64 + f * 16 + l15) * 32 + cl * 8;
  }

  // prologue: ht[0..5] = A(0,0) B(0,0) A(0,1) B(0,1) A(1,0) B(1,0)
  // stage(tt,hh): slot=(2tt+hh)&3, koff=tt*64+hh*32 (all compile-time below)
#define STAGE_A(tt, hh)                                                        \
  {                                                                            \
    gload16(aptr0 + ((tt) * 64 + (hh) * 32), Ad + ((((2 * (tt) + (hh)) & 3)) << 13)); \
    gload16(aptr1 + ((tt) * 64 + (hh) * 32), Ad + ((((2 * (tt) + (hh)) & 3)) << 13) + 4096); \
  }
#define STAGE_B(tt, hh)                                                        \
  {                                                                            \
    gload16(bptr0 + ((tt) * 64 + (hh) * 32), Bd + ((((2 * (tt) + (hh)) & 3)) << 13)); \
    gload16(bptr1 + ((tt) * 64 + (hh) * 32), Bd + ((((2 * (tt) + (hh)) & 3)) << 13) + 4096); \
  }

  STAGE_A(0, 0); STAGE_B(0, 0); STAGE_A(0, 1); STAGE_B(0, 1);
  __builtin_amdgcn_sched_barrier(0);
  STAGE_A(1, 0); STAGE_B(1, 0);
  __builtin_amdgcn_sched_barrier(0);
  asm volatile("s_waitcnt vmcnt(4)" ::: "memory");  // K-tile 0 landed
  __builtin_amdgcn_s_barrier();
  __builtin_amdgcn_sched_barrier(0);

  f32x4 acc[8][4] = {};
  bf16x8 bfr[4];

#pragma unroll
  for (int t = 0; t < NT; ++t) {
#pragma unroll
    for (int q = 0; q < 4; ++q) {
      const int h = q >> 1, mh = q & 1;
      const int slot = (2 * t + h) & 3;                 // compile-time
      const int roff = (slot << 13) + mh * 2048;        // element offset: slot*8192 + mh*64rows*32
      bf16x8 af[4];
#pragma unroll
      for (int f = 0; f < 4; ++f) af[f] = *(const bf16x8*)(arb[f] + roff);
      if (mh == 0) {
#pragma unroll
        for (int f = 0; f < 4; ++f) bfr[f] = *(const bf16x8*)(brb[f] + (slot << 13));
      }
      // stage ht[p+6]
      if (q == 0)      { if (t + 1 < NT) STAGE_A(t + 1, 1); }
      else if (q == 1) { if (t + 1 < NT) STAGE_B(t + 1, 1); }
      else if (q == 2) { if (t + 2 < NT) STAGE_A(t + 2, 0); }
      else             { if (t + 2 < NT) STAGE_B(t + 2, 0); }
      __builtin_amdgcn_s_barrier();
      __builtin_amdgcn_s_setprio(1);
#pragma unroll
      for (int fm = 0; fm < 4; ++fm)
#pragma unroll
        for (int fn = 0; fn < 4; ++fn)
          acc[mh * 4 + fm][fn] = MFMA_BF16(af[fm], bfr[fn], acc[mh * 4 + fm][fn], 0, 0, 0);
      __builtin_amdgcn_s_setprio(0);
      if (q == 3) {
        if (t < NT - 2) asm volatile("s_waitcnt vmcnt(4)" ::: "memory");
        else            asm volatile("s_waitcnt vmcnt(0)" ::: "memory");
      }
      __builtin_amdgcn_sched_barrier(0);
      __builtin_amdgcn_s_barrier();
      __builtin_amdgcn_sched_barrier(0);
    }
  }
#undef STAGE_A
#undef STAGE_B

#pragma unroll
  for (int fn = 0; fn < 4; ++fn) {
    int n = n0 + wn * 64 + fn * 16 + l15;
    if (n < N) {
      float bv = 0.f;
      if (PROJ) bv = bias[n];
#pragma unroll
      for (int a = 0; a < 8; ++a) {
        int mb = m0 + wm * 128 + (a >> 2) * 64 + (a & 3) * 16 + hi * 4;
#pragma unroll
        for (int r = 0; r < 4; ++r) {
          int m = mb + r;
          if (m < M) {
            if (PROJ)
              ((float*)Cout)[remap_row<REMAP>(m) * N + n] = acc[a][fn][r] + bv;
            else
              ((unsigned short*)Cout)[(long)m * N + n] = f2bf(acc[a][fn][r]);
          }
        }
      }
    }
  }
}

// ============ 128x128 tile GEMM (kept for the two small GEMMs) ============
template <int REMAP, bool PROJ>
__global__ void __launch_bounds__(256) gemm_bt(const unsigned short* __restrict__ A,
                                               const unsigned short* __restrict__ Bw,
                                               void* __restrict__ Cout,
                                               const float* __restrict__ bias,
                                               int M, int N) {
  const int K = 1152;
  __shared__ unsigned short At[128 * 64];
  __shared__ unsigned short Bt[128 * 64];
  int tid = threadIdx.x;
  int lane = tid & 63, wid = tid >> 6;
  int l15 = lane & 15, hi = lane >> 4;
  int wm = wid >> 1, wn = wid & 1;
  int m0 = blockIdx.y * 128, n0 = blockIdx.x * 128;

  const unsigned short* asrc[4];
  const unsigned short* bsrc[4];
  unsigned ldsoff[4];
#pragma unroll
  for (int j = 0; j < 4; j++) {
    int c = tid + j * 256;
    int r = c >> 3;
    int cc = (c & 7) ^ (r & 7);
    ldsoff[j] = (unsigned)c * 8;
    int ma = m0 + r; if (ma > M - 1) ma = M - 1;
    asrc[j] = A + remap_row<REMAP>(ma) * K + cc * 8;
    bsrc[j] = Bw + (long)(n0 + r) * K + cc * 8;
  }

  f32x4 acc[4][4] = {};

  for (int kt = 0; kt < K; kt += 64) {
#pragma unroll
    for (int j = 0; j < 4; j++) {
      gload16(asrc[j] + kt, &At[ldsoff[j]]);
      gload16(bsrc[j] + kt, &Bt[ldsoff[j]]);
    }
    __syncthreads();
#pragma unroll
    for (int ks = 0; ks < 2; ks++) {
      bf16x8 af[4], bfr[4];
#pragma unroll
      for (int i = 0; i < 4; i++) {
        int ra = wm * 64 + i * 16 + l15;
        int ca = (ks * 64 + hi * 16) ^ ((ra & 7) << 4);
        af[i] = *(const bf16x8*)((const char*)At + ra * 128 + ca);
        int rb = wn * 64 + i * 16 + l15;
        int cb = (ks * 64 + hi * 16) ^ ((rb & 7) << 4);
        bfr[i] = *(const bf16x8*)((const char*)Bt + rb * 128 + cb);
      }
#pragma unroll
      for (int i = 0; i < 4; i++)
#pragma unroll
        for (int j = 0; j < 4; j++)
          acc[i][j] = MFMA_BF16(af[i], bfr[j], acc[i][j], 0, 0, 0);
    }
    __syncthreads();
  }

#pragma unroll
  for (int j = 0; j < 4; j++) {
    int n = n0 + wn * 64 + j * 16 + l15;
    float bv = 0.f;
    if (PROJ) bv = bias[n];
#pragma unroll
    for (int i = 0; i < 4; i++) {
      int mb = m0 + wm * 64 + i * 16 + hi * 4;
#pragma unroll
      for (int r = 0; r < 4; r++) {
        int m = mb + r;
        if (m < M) {
          if (PROJ)
            ((float*)Cout)[remap_row<REMAP>(m) * N + n] = acc[i][j][r] + bv;
          else
            ((unsigned short*)Cout)[(long)m * N + n] = f2bf(acc[i][j][r]);
        }
      }
    }
  }
}

// ---- non-act attention: one block per (h, g, b); 4 waves, each owns 64 q rows ----
__global__ void __launch_bounds__(256) attn_non(const unsigned short* __restrict__ qkv,
                                                unsigned short* __restrict__ o) {
  int h = blockIdx.x, g = blockIdx.y, b = blockIdx.z;
  __shared__ unsigned short K_s[128 * 104];
  __shared__ unsigned short V_s[80 * 136];
  __shared__ unsigned short P_s[16 * 16 * 40];
  int tid = threadIdx.x, lane = tid & 63, wid = tid >> 6;
  int l15 = lane & 15, hi = lane >> 4;
  const long base = (long)((b * 3 + g) * 256) * 3456;
  const float SC2 = 0.11785113019775793f * 1.4426950408889634f;

  bf16x8 qf[4][3];
#pragma unroll
  for (int qt = 0; qt < 4; qt++)
#pragma unroll
    for (int ds = 0; ds < 3; ds++) {
      int q = wid * 64 + qt * 16 + l15;
      int d = ds * 32 + hi * 8;
      if (d < 72)
        qf[qt][ds] = *(const bf16x8*)(qkv + base + (long)q * 3456 + h * 72 + d);
      else {
        u16x8 z = {0, 0, 0, 0, 0, 0, 0, 0};
        qf[qt][ds] = __builtin_bit_cast(bf16x8, z);
      }
    }

  f32x4 ot[5][4] = {};
  float lsum[4] = {0.f, 0.f, 0.f, 0.f};

  for (int c0 = 0; c0 < 256; c0 += 128) {
    {
      int r = tid >> 1, hf = tid & 1;
      const unsigned short* src = qkv + base + (long)(c0 + r) * 3456 + (16 + h) * 72 + hf * 48;
      unsigned short* dst = &K_s[r * 104 + hf * 48];
#pragma unroll
      for (int j = 0; j < 6; j++) {
        int col = hf * 48 + j * 8;
        u16x8 v = {0, 0, 0, 0, 0, 0, 0, 0};
        if (col < 72) v = *(const u16x8*)(src + j * 8);
        *(u16x8*)(dst + j * 8) = v;
      }
    }
    if (tid < 128) {
      const unsigned short* src = qkv + base + (long)(c0 + tid) * 3456 + (32 + h) * 72;
      u16x8 w[9];
#pragma unroll
      for (int j = 0; j < 9; j++) w[j] = *(const u16x8*)(src + j * 8);
#pragma unroll
      for (int j = 0; j < 9; j++)
#pragma unroll
        for (int e = 0; e < 8; e++) V_s[(j * 8 + e) * 136 + tid] = w[j][e];
    }
    __syncthreads();

#pragma unroll
    for (int k32 = 0; k32 < 4; k32++) {
#pragma unroll
      for (int kt = 0; kt < 2; kt++) {
        bf16x8 kf[3];
#pragma unroll
        for (int ds = 0; ds < 3; ds++)
          kf[ds] = *(const bf16x8*)((const char*)K_s +
                     ((k32 * 32 + kt * 16 + l15) * 104 + ds * 32 + hi * 8) * 2);
#pragma unroll
        for (int qt = 0; qt < 4; qt++) {
          f32x4 st = {};
#pragma unroll
          for (int ds = 0; ds < 3; ds++) st = MFMA_BF16(kf[ds], qf[qt][ds], st, 0, 0, 0);
          u16x4 pw;
#pragma unroll
          for (int r = 0; r < 4; r++) {
            float p = exp2f(st[r] * SC2);
            lsum[qt] += p;
            pw[r] = f2bf(p);
          }
          *(u16x4*)&P_s[((wid * 4 + qt) * 16 + l15) * 40 + kt * 16 + hi * 4] = pw;
        }
      }
      bf16x8 pf[4];
#pragma unroll
      for (int qt = 0; qt < 4; qt++)
        pf[qt] = *(const bf16x8*)&P_s[((wid * 4 + qt) * 16 + l15) * 40 + hi * 8];
#pragma unroll
      for (int dt = 0; dt < 5; dt++) {
        bf16x8 vf = *(const bf16x8*)&V_s[(dt * 16 + l15) * 136 + k32 * 32 + hi * 8];
#pragma unroll
        for (int qt = 0; qt < 4; qt++) ot[dt][qt] = MFMA_BF16(vf, pf[qt], ot[dt][qt], 0, 0, 0);
      }
    }
    __syncthreads();
  }

#pragma unroll
  for (int qt = 0; qt < 4; qt++) {
    float s = lsum[qt];
    s += __shfl_xor(s, 16);
    s += __shfl_xor(s, 32);
    lsum[qt] = 1.0f / s;
  }
#pragma unroll
  for (int dt = 0; dt < 5; dt++)
#pragma unroll
    for (int qt = 0; qt < 4; qt++)
#pragma unroll
      for (int r = 0; r < 4; r++) {
        int d = dt * 16 + hi * 4 + r;
        if (d < 72) {
          long row = (long)b * 825 + 57 + g * 256 + wid * 64 + qt * 16 + l15;
          o[row * 1152 + h * 72 + d] = f2bf(ot[dt][qt][r] * lsum[qt]);
        }
      }
}

// ---- act attention: one block per (h, b); 4 waves, each owns one 16-q tile (57 q) ----
__global__ void __launch_bounds__(256) attn_act(const unsigned short* __restrict__ kv,
                                                const unsigned short* __restrict__ qa,
                                                unsigned short* __restrict__ o) {
  int h = blockIdx.x, b = blockIdx.y;
  __shared__ unsigned short K_s[128 * 104];
  __shared__ unsigned short V_s[80 * 136];
  __shared__ unsigned short P_s[4 * 16 * 40];
  int tid = threadIdx.x, lane = tid & 63, wid = tid >> 6;
  int l15 = lane & 15, hi = lane >> 4;
  const float SC2 = 0.11785113019775793f * 1.4426950408889634f;
  const int LIM = 769;

  bf16x8 qf[3];
  {
    int q = wid * 16 + l15; if (q > 56) q = 56;
#pragma unroll
    for (int ds = 0; ds < 3; ds++) {
      int d = ds * 32 + hi * 8;
      if (d < 72)
        qf[ds] = *(const bf16x8*)(qa + (long)(b * 57 + q) * 1152 + h * 72 + d);
      else {
        u16x8 z = {0, 0, 0, 0, 0, 0, 0, 0};
        qf[ds] = __builtin_bit_cast(bf16x8, z);
      }
    }
  }

  f32x4 ot[5] = {};
  float lsum = 0.f;
  const long kbase = (long)b * 825 + 56;

  for (int c0 = 0; c0 < LIM; c0 += 128) {
    int valid = LIM - c0; if (valid > 128) valid = 128;
    {
      int r = tid >> 1, hf = tid & 1;
      int rr = r < valid ? r : valid - 1;
      const unsigned short* src = kv + (kbase + c0 + rr) * 2304 + h * 72 + hf * 48;
      unsigned short* dst = &K_s[r * 104 + hf * 48];
#pragma unroll
      for (int j = 0; j < 6; j++) {
        int col = hf * 48 + j * 8;
        u16x8 v = {0, 0, 0, 0, 0, 0, 0, 0};
        if (col < 72) v = *(const u16x8*)(src + j * 8);
        *(u16x8*)(dst + j * 8) = v;
      }
    }
    if (tid < 128) {
      int rr = tid < valid ? tid : valid - 1;
      const unsigned short* src = kv + (kbase + c0 + rr) * 2304 + (16 + h) * 72;
      u16x8 w[9];
#pragma unroll
      for (int j = 0; j < 9; j++) w[j] = *(const u16x8*)(src + j * 8);
#pragma unroll
      for (int j = 0; j < 9; j++)
#pragma unroll
        for (int e = 0; e < 8; e++) V_s[(j * 8 + e) * 136 + tid] = w[j][e];
    }
    __syncthreads();

#pragma unroll
    for (int k32 = 0; k32 < 4; k32++) {
#pragma unroll
      for (int kt = 0; kt < 2; kt++) {
        bf16x8 kf[3];
#pragma unroll
        for (int ds = 0; ds < 3; ds++)
          kf[ds] = *(const bf16x8*)((const char*)K_s +
                     ((k32 * 32 + kt * 16 + l15) * 104 + ds * 32 + hi * 8) * 2);
        f32x4 st = {};
#pragma unroll
        for (int ds = 0; ds < 3; ds++) st = MFMA_BF16(kf[ds], qf[ds], st, 0, 0, 0);
        u16x4 pw;
#pragma unroll
        for (int r = 0; r < 4; r++) {
          int kg = c0 + k32 * 32 + kt * 16 + hi * 4 + r;
          float p = (kg < LIM) ? exp2f(st[r] * SC2) : 0.f;
          lsum += p;
          pw[r] = f2bf(p);
        }
        *(u16x4*)&P_s[(wid * 16 + l15) * 40 + kt * 16 + hi * 4] = pw;
      }
      bf16x8 pf = *(const bf16x8*)&P_s[(wid * 16 + l15) * 40 + hi * 8];
#pragma unroll
      for (int dt = 0; dt < 5; dt++) {
        bf16x8 vf = *(const bf16x8*)&V_s[(dt * 16 + l15) * 136 + k32 * 32 + hi * 8];
        ot[dt] = MFMA_BF16(vf, pf, ot[dt], 0, 0, 0);
      }
    }
    __syncthreads();
  }

  {
    float s = lsum;
    s += __shfl_xor(s, 16);
    s += __shfl_xor(s, 32);
    lsum = 1.0f / s;
  }
  int q = wid * 16 + l15;
#pragma unroll
  for (int dt = 0; dt < 5; dt++)
#pragma unroll
    for (int r = 0; r < 4; r++) {
      int d = dt * 16 + hi * 4 + r;
      if (d < 72 && q < 57)
        o[((long)b * 825 + q) * 1152 + h * 72 + d] = f2bf(ot[dt][r] * lsum);
    }
}

extern "C" void kernel_launch(void* const* d_in, const int* in_sizes, int n_in,
                              void* d_out, int out_size, void* d_ws, size_t ws_size,
                              hipStream_t stream) {
  const float* x     = (const float*)d_in[0];
  const float* w_qkv = (const float*)d_in[1];
  const float* w_q   = (const float*)d_in[2];
  const float* w_kv  = (const float*)d_in[3];
  const float* w_pn  = (const float*)d_in[4];
  const float* b_pn  = (const float*)d_in[5];
  const float* w_pa  = (const float*)d_in[6];
  const float* b_pa  = (const float*)d_in[7];

  char* ws = (char*)d_ws;
  unsigned short* xb    = (unsigned short*)ws; ws += (size_t)26400 * 1152 * 2;
  unsigned short* wqkvb = (unsigned short*)ws; ws += (size_t)3456 * 1152 * 2;
  unsigned short* wqb   = (unsigned short*)ws; ws += (size_t)1152 * 1152 * 2;
  unsigned short* wkvb  = (unsigned short*)ws; ws += (size_t)2304 * 1152 * 2;
  unsigned short* wpnb  = (unsigned short*)ws; ws += (size_t)1152 * 1152 * 2;
  unsigned short* wpab  = (unsigned short*)ws; ws += (size_t)1152 * 1152 * 2;
  unsigned short* qkvw  = (unsigned short*)ws; ws += (size_t)24576 * 3456 * 2;
  unsigned short* kvw   = (unsigned short*)ws; ws += (size_t)26400 * 2304 * 2;
  unsigned short* qw    = (unsigned short*)ws; ws += (size_t)1824 * 1152 * 2;
  unsigned short* attnw = (unsigned short*)ws; ws += (size_t)26400 * 1152 * 2;

  auto cast = [&](const float* src, unsigned short* dst, long n) {
    int n8 = (int)(n / 8);
    cast_bf16_kernel<<<(n8 + 255) / 256, 256, 0, stream>>>(src, dst, n8);
  };
  cast(x,     xb,    26400L * 1152);
  cast(w_qkv, wqkvb, 3456L * 1152);
  cast(w_q,   wqb,   1152L * 1152);
  cast(w_kv,  wkvb,  2304L * 1152);
  cast(w_pn,  wpnb,  1152L * 1152);
  cast(w_pa,  wpab,  1152L * 1152);

  // qkv_non = x[:,57:] @ w_qkv^T   (M=24576, N=3456): 96 x 14 tiles
  gemm256<1, false><<<dim3(14, 96), 512, 0, stream>>>(xb, wqkvb, qkvw, nullptr, 24576, 3456);
  // kv_act = x @ w_kv^T            (M=26400, N=2304): 104 x 9 tiles
  gemm256<0, false><<<dim3(9, 104), 512, 0, stream>>>(xb, wkvb, kvw, nullptr, 26400, 2304);
  // q_act = x[:,:57] @ w_q^T       (M=1824, N=1152) - small, 128-tile path
  gemm_bt<2, false><<<dim3(9, 15), 256, 0, stream>>>(xb, wqb, qw, nullptr, 1824, 1152);

  attn_non<<<dim3(16, 3, 32), 256, 0, stream>>>(qkvw, attnw);
  attn_act<<<dim3(16, 32), 256, 0, stream>>>(kvw, qw, attnw);

  // projections into d_out (fp32), rows remapped to [act | non] layout
  gemm256<1, true><<<dim3(5, 96), 512, 0, stream>>>(attnw, wpnb, d_out, b_pn, 24576, 1152);
  gemm_bt<2, true><<<dim3(9, 15), 256, 0, stream>>>(attnw, wpab, d_out, b_pa, 1824, 1152);
}

// Round 5
// 738.203 us; speedup vs baseline: 1.2009x; 1.1014x over previous
//
#include <hip/hip_runtime.h>

typedef __attribute__((ext_vector_type(8))) __bf16 bf16x8;
typedef __attribute__((ext_vector_type(4))) float f32x4;
typedef __attribute__((ext_vector_type(4))) unsigned short u16x4;
typedef __attribute__((ext_vector_type(8))) unsigned short u16x8;

#define MFMA_BF16 __builtin_amdgcn_mfma_f32_16x16x32_bf16

__device__ __forceinline__ unsigned short f2bf(float f) {
  union { float f; unsigned u; } v; v.f = f;
  unsigned r = v.u + 0x7FFFu + ((v.u >> 16) & 1u);
  return (unsigned short)(r >> 16);
}

__device__ __forceinline__ void gload16(const void* g, void* l) {
  __builtin_amdgcn_global_load_lds(
      (const __attribute__((address_space(1))) unsigned int*)g,
      (__attribute__((address_space(3))) unsigned int*)l, 16, 0, 0);
}

__global__ void __launch_bounds__(256) cast_bf16_kernel(const float* __restrict__ in,
                                                        unsigned short* __restrict__ out,
                                                        int n8) {
  int i = blockIdx.x * 256 + threadIdx.x;
  if (i >= n8) return;
  long base = (long)i * 8;
  float4 a = *(const float4*)(in + base);
  float4 b = *(const float4*)(in + base + 4);
  u16x8 o;
  o[0] = f2bf(a.x); o[1] = f2bf(a.y); o[2] = f2bf(a.z); o[3] = f2bf(a.w);
  o[4] = f2bf(b.x); o[5] = f2bf(b.y); o[6] = f2bf(b.z); o[7] = f2bf(b.w);
  *(u16x8*)(out + base) = o;
}

// row remapping: 0 = identity, 1 = b*825 + 57 + (m % 768), 2 = b*825 + (m % 57)
template <int REMAP>
__device__ __forceinline__ long remap_row(int m) {
  if (REMAP == 1) { int b = m / 768; return (long)b * 825 + 57 + (m - b * 768); }
  if (REMAP == 2) { int b = m / 57;  return (long)b * 825 + (m - b * 57); }
  return m;
}

// ============ 256x256 tile, BK=64, 8-wave, 4-phase/K-tile counted-vmcnt GEMM ============
// Single post-MFMA barrier per phase (pre-MFMA barrier removed; slot ledger still holds:
// every slot's last read and its re-stage are separated by >=1 barrier, and vmcnt(4)
// precedes the barrier so all waves' staged slices land before any wave reads the slot).
// Waves skew by <=1 phase, overlapping ds_read/stage with other waves' MFMA clusters.
template <int REMAP, bool PROJ>
__global__ void __launch_bounds__(512, 2) gemm256(const unsigned short* __restrict__ A,
                                                  const unsigned short* __restrict__ Bw,
                                                  void* __restrict__ Cout,
                                                  const float* __restrict__ bias,
                                                  int M, int N) {
  const int K = 1152;
  const int NT = 18;  // K / 64
  __shared__ unsigned short L[65536];  // 128 KiB: A slots [0,32768), B slots [32768,65536)
  unsigned short* Al = L;
  unsigned short* Bl = L + 32768;
  int tid = threadIdx.x;
  int lane = tid & 63;
  int wid = tid >> 6;
  int l15 = lane & 15, hi = lane >> 4;
  int wm = wid >> 2, wn = wid & 3;

  // bijective XCD swizzle (all grids used are divisible by 8)
  int gx = gridDim.x;
  int nwg = gx * gridDim.y;
  int orig = blockIdx.y * gx + blockIdx.x;
  int q8 = nwg >> 3, r8 = nwg & 7;
  int xcd = orig & 7, off = orig >> 3;
  int wgid = (xcd < r8 ? xcd * (q8 + 1) : r8 * (q8 + 1) + (xcd - r8) * q8) + off;
  int bn = wgid % gx, bm = wgid / gx;
  int m0 = bm * 256, n0 = bn * 256;

  // staging geometry: thread stages 16B at slot-bytes tid*16 and tid*16+8192
  int rlo = tid >> 2;                      // 0..127 (row within half)
  int cg = ((tid & 3) - (tid >> 3)) & 3;   // global k-chunk for physical chunk (tid&3)
  int ma0 = m0 + rlo;       if (ma0 > M - 1) ma0 = M - 1;
  int ma1 = m0 + rlo + 128; if (ma1 > M - 1) ma1 = M - 1;
  const unsigned short* aptr0 = A + remap_row<REMAP>(ma0) * K + cg * 8;
  const unsigned short* aptr1 = A + remap_row<REMAP>(ma1) * K + cg * 8;
  int nb0 = n0 + rlo;       if (nb0 > N - 1) nb0 = N - 1;
  int nb1 = n0 + rlo + 128; if (nb1 > N - 1) nb1 = N - 1;
  const unsigned short* bptr0 = Bw + (long)nb0 * K + cg * 8;
  const unsigned short* bptr1 = Bw + (long)nb1 * K + cg * 8;
  unsigned ldst = (unsigned)tid * 8;  // element offset within slot

  unsigned short* Ad = Al + ldst;
  unsigned short* Bd = Bl + ldst;

  // hoisted ds_read base addresses (slot and mh become immediate offsets)
  const int cl = (hi + (l15 >> 1)) & 3;  // physical chunk for logical chunk hi
  const unsigned short* arb[4];
  const unsigned short* brb[4];
#pragma unroll
  for (int f = 0; f < 4; ++f) {
    arb[f] = Al + (wm * 128 + f * 16 + l15) * 32 + cl * 8;
    brb[f] = Bl + (wn * 64 + f * 16 + l15) * 32 + cl * 8;
  }

#define STAGE_A(tt, hh)                                                        \
  {                                                                            \
    gload16(aptr0 + ((tt) * 64 + (hh) * 32), Ad + ((((2 * (tt) + (hh)) & 3)) << 13)); \
    gload16(aptr1 + ((tt) * 64 + (hh) * 32), Ad + ((((2 * (tt) + (hh)) & 3)) << 13) + 4096); \
  }
#define STAGE_B(tt, hh)                                                        \
  {                                                                            \
    gload16(bptr0 + ((tt) * 64 + (hh) * 32), Bd + ((((2 * (tt) + (hh)) & 3)) << 13)); \
    gload16(bptr1 + ((tt) * 64 + (hh) * 32), Bd + ((((2 * (tt) + (hh)) & 3)) << 13) + 4096); \
  }

  STAGE_A(0, 0); STAGE_B(0, 0); STAGE_A(0, 1); STAGE_B(0, 1);
  __builtin_amdgcn_sched_barrier(0);
  STAGE_A(1, 0); STAGE_B(1, 0);
  __builtin_amdgcn_sched_barrier(0);
  asm volatile("s_waitcnt vmcnt(4)" ::: "memory");  // K-tile 0 landed
  __builtin_amdgcn_s_barrier();
  __builtin_amdgcn_sched_barrier(0);

  f32x4 acc[8][4] = {};
  bf16x8 bfr[4];

#pragma unroll
  for (int t = 0; t < NT; ++t) {
#pragma unroll
    for (int q = 0; q < 4; ++q) {
      const int h = q >> 1, mh = q & 1;
      const int slot = (2 * t + h) & 3;                 // compile-time
      const int roff = (slot << 13) + mh * 2048;
      bf16x8 af[4];
#pragma unroll
      for (int f = 0; f < 4; ++f) af[f] = *(const bf16x8*)(arb[f] + roff);
      if (mh == 0) {
#pragma unroll
        for (int f = 0; f < 4; ++f) bfr[f] = *(const bf16x8*)(brb[f] + (slot << 13));
      }
      // stage ht[p+6]
      if (q == 0)      { if (t + 1 < NT) STAGE_A(t + 1, 1); }
      else if (q == 1) { if (t + 1 < NT) STAGE_B(t + 1, 1); }
      else if (q == 2) { if (t + 2 < NT) STAGE_A(t + 2, 0); }
      else             { if (t + 2 < NT) STAGE_B(t + 2, 0); }
      __builtin_amdgcn_s_setprio(1);
#pragma unroll
      for (int fm = 0; fm < 4; ++fm)
#pragma unroll
        for (int fn = 0; fn < 4; ++fn)
          acc[mh * 4 + fm][fn] = MFMA_BF16(af[fm], bfr[fn], acc[mh * 4 + fm][fn], 0, 0, 0);
      __builtin_amdgcn_s_setprio(0);
      if (q == 3) {
        if (t < NT - 2) asm volatile("s_waitcnt vmcnt(4)" ::: "memory");
        else            asm volatile("s_waitcnt vmcnt(0)" ::: "memory");
      }
      __builtin_amdgcn_sched_barrier(0);
      __builtin_amdgcn_s_barrier();
      __builtin_amdgcn_sched_barrier(0);
    }
  }
#undef STAGE_A
#undef STAGE_B

  // ======== epilogue via per-wave-private LDS region -> coalesced 16B stores ========
  if (!PROJ) {
    unsigned short* reg = L + wid * 8192;  // [128][8 chunks of 8] u16, chunk XOR row&7
#pragma unroll
    for (int a = 0; a < 8; ++a) {
#pragma unroll
      for (int fn = 0; fn < 4; ++fn) {
        int rbase = (a >> 2) * 64 + (a & 3) * 16 + hi * 4;
#pragma unroll
        for (int r = 0; r < 4; ++r) {
          int row = rbase + r;
          int ch = (fn * 2 + (l15 >> 3)) ^ (row & 7);
          reg[row * 64 + ch * 8 + (l15 & 7)] = f2bf(acc[a][fn][r]);
        }
      }
    }
#pragma unroll
    for (int i = 0; i < 16; ++i) {
      int rr = i * 8 + (lane >> 3);
      int ch = (lane & 7) ^ (rr & 7);
      u16x8 v = *(const u16x8*)(reg + rr * 64 + ch * 8);
      int m = m0 + wm * 128 + rr;
      int n = n0 + wn * 64 + (lane & 7) * 8;
      if (m < M && n < N)
        *(u16x8*)((unsigned short*)Cout + (long)m * N + n) = v;
    }
  } else {
    float* regf = (float*)L + wid * 4096;  // [64][64] f32 = 16KB per wave
    float bv[4];
#pragma unroll
    for (int fn = 0; fn < 4; ++fn) {
      int n = n0 + wn * 64 + fn * 16 + l15;
      bv[fn] = bias[n < N ? n : N - 1];
    }
#pragma unroll
    for (int half = 0; half < 2; ++half) {
#pragma unroll
      for (int a4 = 0; a4 < 4; ++a4) {
#pragma unroll
        for (int fn = 0; fn < 4; ++fn) {
          int rbase = a4 * 16 + hi * 4;
#pragma unroll
          for (int r = 0; r < 4; ++r)
            regf[(rbase + r) * 64 + fn * 16 + l15] = acc[half * 4 + a4][fn][r] + bv[fn];
        }
      }
#pragma unroll
      for (int i = 0; i < 16; ++i) {
        int rr = i * 4 + (lane >> 4);
        int cc = (lane & 15) * 4;
        f32x4 v = *(const f32x4*)(regf + rr * 64 + cc);
        int m = m0 + wm * 128 + half * 64 + rr;
        int n = n0 + wn * 64 + cc;
        if (m < M && n < N)
          *(f32x4*)((float*)Cout + remap_row<REMAP>(m) * N + n) = v;
      }
      if (half == 0) asm volatile("s_waitcnt lgkmcnt(0)" ::: "memory");
    }
  }
}

// ============ 128x128 tile GEMM (kept for the two small GEMMs) ============
template <int REMAP, bool PROJ>
__global__ void __launch_bounds__(256) gemm_bt(const unsigned short* __restrict__ A,
                                               const unsigned short* __restrict__ Bw,
                                               void* __restrict__ Cout,
                                               const float* __restrict__ bias,
                                               int M, int N) {
  const int K = 1152;
  __shared__ unsigned short At[128 * 64];
  __shared__ unsigned short Bt[128 * 64];
  int tid = threadIdx.x;
  int lane = tid & 63, wid = tid >> 6;
  int l15 = lane & 15, hi = lane >> 4;
  int wm = wid >> 1, wn = wid & 1;
  int m0 = blockIdx.y * 128, n0 = blockIdx.x * 128;

  const unsigned short* asrc[4];
  const unsigned short* bsrc[4];
  unsigned ldsoff[4];
#pragma unroll
  for (int j = 0; j < 4; j++) {
    int c = tid + j * 256;
    int r = c >> 3;
    int cc = (c & 7) ^ (r & 7);
    ldsoff[j] = (unsigned)c * 8;
    int ma = m0 + r; if (ma > M - 1) ma = M - 1;
    asrc[j] = A + remap_row<REMAP>(ma) * K + cc * 8;
    bsrc[j] = Bw + (long)(n0 + r) * K + cc * 8;
  }

  f32x4 acc[4][4] = {};

  for (int kt = 0; kt < K; kt += 64) {
#pragma unroll
    for (int j = 0; j < 4; j++) {
      gload16(asrc[j] + kt, &At[ldsoff[j]]);
      gload16(bsrc[j] + kt, &Bt[ldsoff[j]]);
    }
    __syncthreads();
#pragma unroll
    for (int ks = 0; ks < 2; ks++) {
      bf16x8 af[4], bfr[4];
#pragma unroll
      for (int i = 0; i < 4; i++) {
        int ra = wm * 64 + i * 16 + l15;
        int ca = (ks * 64 + hi * 16) ^ ((ra & 7) << 4);
        af[i] = *(const bf16x8*)((const char*)At + ra * 128 + ca);
        int rb = wn * 64 + i * 16 + l15;
        int cb = (ks * 64 + hi * 16) ^ ((rb & 7) << 4);
        bfr[i] = *(const bf16x8*)((const char*)Bt + rb * 128 + cb);
      }
#pragma unroll
      for (int i = 0; i < 4; i++)
#pragma unroll
        for (int j = 0; j < 4; j++)
          acc[i][j] = MFMA_BF16(af[i], bfr[j], acc[i][j], 0, 0, 0);
    }
    __syncthreads();
  }

#pragma unroll
  for (int j = 0; j < 4; j++) {
    int n = n0 + wn * 64 + j * 16 + l15;
    float bv = 0.f;
    if (PROJ) bv = bias[n];
#pragma unroll
    for (int i = 0; i < 4; i++) {
      int mb = m0 + wm * 64 + i * 16 + hi * 4;
#pragma unroll
      for (int r = 0; r < 4; r++) {
        int m = mb + r;
        if (m < M) {
          if (PROJ)
            ((float*)Cout)[remap_row<REMAP>(m) * N + n] = acc[i][j][r] + bv;
          else
            ((unsigned short*)Cout)[(long)m * N + n] = f2bf(acc[i][j][r]);
        }
      }
    }
  }
}

// ---- non-act attention: one block per (h, g, b); 4 waves, each owns 64 q rows ----
__global__ void __launch_bounds__(256) attn_non(const unsigned short* __restrict__ qkv,
                                                unsigned short* __restrict__ o) {
  int h = blockIdx.x, g = blockIdx.y, b = blockIdx.z;
  __shared__ unsigned short K_s[128 * 104];
  __shared__ unsigned short V_s[80 * 136];
  __shared__ unsigned short P_s[16 * 16 * 40];
  int tid = threadIdx.x, lane = tid & 63, wid = tid >> 6;
  int l15 = lane & 15, hi = lane >> 4;
  const long base = (long)((b * 3 + g) * 256) * 3456;
  const float SC2 = 0.11785113019775793f * 1.4426950408889634f;

  bf16x8 qf[4][3];
#pragma unroll
  for (int qt = 0; qt < 4; qt++)
#pragma unroll
    for (int ds = 0; ds < 3; ds++) {
      int q = wid * 64 + qt * 16 + l15;
      int d = ds * 32 + hi * 8;
      if (d < 72)
        qf[qt][ds] = *(const bf16x8*)(qkv + base + (long)q * 3456 + h * 72 + d);
      else {
        u16x8 z = {0, 0, 0, 0, 0, 0, 0, 0};
        qf[qt][ds] = __builtin_bit_cast(bf16x8, z);
      }
    }

  f32x4 ot[5][4] = {};
  float lsum[4] = {0.f, 0.f, 0.f, 0.f};

  for (int c0 = 0; c0 < 256; c0 += 128) {
    {
      int r = tid >> 1, hf = tid & 1;
      const unsigned short* src = qkv + base + (long)(c0 + r) * 3456 + (16 + h) * 72 + hf * 48;
      unsigned short* dst = &K_s[r * 104 + hf * 48];
#pragma unroll
      for (int j = 0; j < 6; j++) {
        int col = hf * 48 + j * 8;
        u16x8 v = {0, 0, 0, 0, 0, 0, 0, 0};
        if (col < 72) v = *(const u16x8*)(src + j * 8);
        *(u16x8*)(dst + j * 8) = v;
      }
    }
    if (tid < 128) {
      const unsigned short* src = qkv + base + (long)(c0 + tid) * 3456 + (32 + h) * 72;
      u16x8 w[9];
#pragma unroll
      for (int j = 0; j < 9; j++) w[j] = *(const u16x8*)(src + j * 8);
#pragma unroll
      for (int j = 0; j < 9; j++)
#pragma unroll
        for (int e = 0; e < 8; e++) V_s[(j * 8 + e) * 136 + tid] = w[j][e];
    }
    __syncthreads();

#pragma unroll
    for (int k32 = 0; k32 < 4; k32++) {
#pragma unroll
      for (int kt = 0; kt < 2; kt++) {
        bf16x8 kf[3];
#pragma unroll
        for (int ds = 0; ds < 3; ds++)
          kf[ds] = *(const bf16x8*)((const char*)K_s +
                     ((k32 * 32 + kt * 16 + l15) * 104 + ds * 32 + hi * 8) * 2);
#pragma unroll
        for (int qt = 0; qt < 4; qt++) {
          f32x4 st = {};
#pragma unroll
          for (int ds = 0; ds < 3; ds++) st = MFMA_BF16(kf[ds], qf[qt][ds], st, 0, 0, 0);
          u16x4 pw;
#pragma unroll
          for (int r = 0; r < 4; r++) {
            float p = exp2f(st[r] * SC2);
            lsum[qt] += p;
            pw[r] = f2bf(p);
          }
          *(u16x4*)&P_s[((wid * 4 + qt) * 16 + l15) * 40 + kt * 16 + hi * 4] = pw;
        }
      }
      bf16x8 pf[4];
#pragma unroll
      for (int qt = 0; qt < 4; qt++)
        pf[qt] = *(const bf16x8*)&P_s[((wid * 4 + qt) * 16 + l15) * 40 + hi * 8];
#pragma unroll
      for (int dt = 0; dt < 5; dt++) {
        bf16x8 vf = *(const bf16x8*)&V_s[(dt * 16 + l15) * 136 + k32 * 32 + hi * 8];
#pragma unroll
        for (int qt = 0; qt < 4; qt++) ot[dt][qt] = MFMA_BF16(vf, pf[qt], ot[dt][qt], 0, 0, 0);
      }
    }
    __syncthreads();
  }

#pragma unroll
  for (int qt = 0; qt < 4; qt++) {
    float s = lsum[qt];
    s += __shfl_xor(s, 16);
    s += __shfl_xor(s, 32);
    lsum[qt] = 1.0f / s;
  }
#pragma unroll
  for (int dt = 0; dt < 5; dt++)
#pragma unroll
    for (int qt = 0; qt < 4; qt++)
#pragma unroll
      for (int r = 0; r < 4; r++) {
        int d = dt * 16 + hi * 4 + r;
        if (d < 72) {
          long row = (long)b * 825 + 57 + g * 256 + wid * 64 + qt * 16 + l15;
          o[row * 1152 + h * 72 + d] = f2bf(ot[dt][qt][r] * lsum[qt]);
        }
      }
}

// ---- act attention: one block per (h, b); 4 waves, each owns one 16-q tile (57 q) ----
__global__ void __launch_bounds__(256) attn_act(const unsigned short* __restrict__ kv,
                                                const unsigned short* __restrict__ qa,
                                                unsigned short* __restrict__ o) {
  int h = blockIdx.x, b = blockIdx.y;
  __shared__ unsigned short K_s[128 * 104];
  __shared__ unsigned short V_s[80 * 136];
  __shared__ unsigned short P_s[4 * 16 * 40];
  int tid = threadIdx.x, lane = tid & 63, wid = tid >> 6;
  int l15 = lane & 15, hi = lane >> 4;
  const float SC2 = 0.11785113019775793f * 1.4426950408889634f;
  const int LIM = 769;

  bf16x8 qf[3];
  {
    int q = wid * 16 + l15; if (q > 56) q = 56;
#pragma unroll
    for (int ds = 0; ds < 3; ds++) {
      int d = ds * 32 + hi * 8;
      if (d < 72)
        qf[ds] = *(const bf16x8*)(qa + (long)(b * 57 + q) * 1152 + h * 72 + d);
      else {
        u16x8 z = {0, 0, 0, 0, 0, 0, 0, 0};
        qf[ds] = __builtin_bit_cast(bf16x8, z);
      }
    }
  }

  f32x4 ot[5] = {};
  float lsum = 0.f;
  const long kbase = (long)b * 825 + 56;

  for (int c0 = 0; c0 < LIM; c0 += 128) {
    int valid = LIM - c0; if (valid > 128) valid = 128;
    {
      int r = tid >> 1, hf = tid & 1;
      int rr = r < valid ? r : valid - 1;
      const unsigned short* src = kv + (kbase + c0 + rr) * 2304 + h * 72 + hf * 48;
      unsigned short* dst = &K_s[r * 104 + hf * 48];
#pragma unroll
      for (int j = 0; j < 6; j++) {
        int col = hf * 48 + j * 8;
        u16x8 v = {0, 0, 0, 0, 0, 0, 0, 0};
        if (col < 72) v = *(const u16x8*)(src + j * 8);
        *(u16x8*)(dst + j * 8) = v;
      }
    }
    if (tid < 128) {
      int rr = tid < valid ? tid : valid - 1;
      const unsigned short* src = kv + (kbase + c0 + rr) * 2304 + (16 + h) * 72;
      u16x8 w[9];
#pragma unroll
      for (int j = 0; j < 9; j++) w[j] = *(const u16x8*)(src + j * 8);
#pragma unroll
      for (int j = 0; j < 9; j++)
#pragma unroll
        for (int e = 0; e < 8; e++) V_s[(j * 8 + e) * 136 + tid] = w[j][e];
    }
    __syncthreads();

#pragma unroll
    for (int k32 = 0; k32 < 4; k32++) {
#pragma unroll
      for (int kt = 0; kt < 2; kt++) {
        bf16x8 kf[3];
#pragma unroll
        for (int ds = 0; ds < 3; ds++)
          kf[ds] = *(const bf16x8*)((const char*)K_s +
                     ((k32 * 32 + kt * 16 + l15) * 104 + ds * 32 + hi * 8) * 2);
        f32x4 st = {};
#pragma unroll
        for (int ds = 0; ds < 3; ds++) st = MFMA_BF16(kf[ds], qf[ds], st, 0, 0, 0);
        u16x4 pw;
#pragma unroll
        for (int r = 0; r < 4; r++) {
          int kg = c0 + k32 * 32 + kt * 16 + hi * 4 + r;
          float p = (kg < LIM) ? exp2f(st[r] * SC2) : 0.f;
          lsum += p;
          pw[r] = f2bf(p);
        }
        *(u16x4*)&P_s[(wid * 16 + l15) * 40 + kt * 16 + hi * 4] = pw;
      }
      bf16x8 pf = *(const bf16x8*)&P_s[(wid * 16 + l15) * 40 + hi * 8];
#pragma unroll
      for (int dt = 0; dt < 5; dt++) {
        bf16x8 vf = *(const bf16x8*)&V_s[(dt * 16 + l15) * 136 + k32 * 32 + hi * 8];
        ot[dt] = MFMA_BF16(vf, pf, ot[dt], 0, 0, 0);
      }
    }
    __syncthreads();
  }

  {
    float s = lsum;
    s += __shfl_xor(s, 16);
    s += __shfl_xor(s, 32);
    lsum = 1.0f / s;
  }
  int q = wid * 16 + l15;
#pragma unroll
  for (int dt = 0; dt < 5; dt++)
#pragma unroll
    for (int r = 0; r < 4; r++) {
      int d = dt * 16 + hi * 4 + r;
      if (d < 72 && q < 57)
        o[((long)b * 825 + q) * 1152 + h * 72 + d] = f2bf(ot[dt][r] * lsum);
    }
}

extern "C" void kernel_launch(void* const* d_in, const int* in_sizes, int n_in,
                              void* d_out, int out_size, void* d_ws, size_t ws_size,
                              hipStream_t stream) {
  const float* x     = (const float*)d_in[0];
  const float* w_qkv = (const float*)d_in[1];
  const float* w_q   = (const float*)d_in[2];
  const float* w_kv  = (const float*)d_in[3];
  const float* w_pn  = (const float*)d_in[4];
  const float* b_pn  = (const float*)d_in[5];
  const float* w_pa  = (const float*)d_in[6];
  const float* b_pa  = (const float*)d_in[7];

  char* ws = (char*)d_ws;
  unsigned short* xb    = (unsigned short*)ws; ws += (size_t)26400 * 1152 * 2;
  unsigned short* wqkvb = (unsigned short*)ws; ws += (size_t)3456 * 1152 * 2;
  unsigned short* wqb   = (unsigned short*)ws; ws += (size_t)1152 * 1152 * 2;
  unsigned short* wkvb  = (unsigned short*)ws; ws += (size_t)2304 * 1152 * 2;
  unsigned short* wpnb  = (unsigned short*)ws; ws += (size_t)1152 * 1152 * 2;
  unsigned short* wpab  = (unsigned short*)ws; ws += (size_t)1152 * 1152 * 2;
  unsigned short* qkvw  = (unsigned short*)ws; ws += (size_t)24576 * 3456 * 2;
  unsigned short* kvw   = (unsigned short*)ws; ws += (size_t)26400 * 2304 * 2;
  unsigned short* qw    = (unsigned short*)ws; ws += (size_t)1824 * 1152 * 2;
  unsigned short* attnw = (unsigned short*)ws; ws += (size_t)26400 * 1152 * 2;

  auto cast = [&](const float* src, unsigned short* dst, long n) {
    int n8 = (int)(n / 8);
    cast_bf16_kernel<<<(n8 + 255) / 256, 256, 0, stream>>>(src, dst, n8);
  };
  cast(x,     xb,    26400L * 1152);
  cast(w_qkv, wqkvb, 3456L * 1152);
  cast(w_q,   wqb,   1152L * 1152);
  cast(w_kv,  wkvb,  2304L * 1152);
  cast(w_pn,  wpnb,  1152L * 1152);
  cast(w_pa,  wpab,  1152L * 1152);

  // qkv_non = x[:,57:] @ w_qkv^T   (M=24576, N=3456): 96 x 14 tiles
  gemm256<1, false><<<dim3(14, 96), 512, 0, stream>>>(xb, wqkvb, qkvw, nullptr, 24576, 3456);
  // kv_act = x @ w_kv^T            (M=26400, N=2304): 104 x 9 tiles
  gemm256<0, false><<<dim3(9, 104), 512, 0, stream>>>(xb, wkvb, kvw, nullptr, 26400, 2304);
  // q_act = x[:,:57] @ w_q^T       (M=1824, N=1152) - small, 128-tile path
  gemm_bt<2, false><<<dim3(9, 15), 256, 0, stream>>>(xb, wqb, qw, nullptr, 1824, 1152);

  attn_non<<<dim3(16, 3, 32), 256, 0, stream>>>(qkvw, attnw);
  attn_act<<<dim3(16, 32), 256, 0, stream>>>(kvw, qw, attnw);

  // projections into d_out (fp32), rows remapped to [act | non] layout
  gemm256<1, true><<<dim3(5, 96), 512, 0, stream>>>(attnw, wpnb, d_out, b_pn, 24576, 1152);
  gemm_bt<2, true><<<dim3(9, 15), 256, 0, stream>>>(attnw, wpab, d_out, b_pa, 1824, 1152);
}